// Round 11
// baseline (223.995 us; speedup 1.0000x reference)
//
#include <hip/hip_runtime.h>
#include <math.h>

#define BB    16
#define PROBN 2048
#define POMO  256
#define ED    128
#define HN    8
#define DDIM  16
#define NEXP  8

typedef _Float16 f16;
typedef f16 f16x2 __attribute__((ext_vector_type(2)));

__device__ __forceinline__ f16x2 f2h(float f) {
  union U { float f; f16x2 h; } u; u.f = f; return u.h;
}
__device__ __forceinline__ float packh2(float a, float b) {
  union U { float f; f16x2 h; } u; u.h.x = (f16)a; u.h.y = (f16)b; return u.f;
}
__device__ __forceinline__ float fdot2f(f16x2 a, f16x2 b, float c) {
#if __has_builtin(__builtin_amdgcn_fdot2)
  return __builtin_amdgcn_fdot2(a, b, c, false);
#else
  return c + (float)a.x * (float)b.x + (float)a.y * (float)b.y;
#endif
}

// ws float offsets (f16 arrays addressed as float*; total ~9.6M floats = 38MB)
#define WS_KH    0                        // f16 K [b][n][h*16+d]    (2,097,152 floats)
#define WS_VHT   (WS_KH + 2097152)        // f16 V^T [b][h*16+d][n]  (2,097,152)
#define WS_NH    (WS_VHT + 2097152)       // f16 nodes [b][n][d]     (2,097,152)
#define WS_QH    (WS_NH + 2097152)        // f16 Q [b*POMO][d]       (262,144)
#define WS_OUT   (WS_QH + 262144)         // f16 attn out [row][64f] (262,144)
#define WS_MH    (WS_OUT + 262144)        // fp32 MoE out            (524,288)
#define WS_WC    (WS_MH + 524288)         // f16 WC pairs [b][p][c]  (131,072)
#define WS_BC    (WS_WC + 131072)         // fp32 combined bias      (2,048)
#define WS_GATES (WS_BC + 2048)

// ---------------------------------------------------------------------------
// K1: gating (top-2 softmax), gates -> ws, moe_loss -> d_out tail.
// STAYS FP32-EXACT: moe_loss is the only strictly-checked output (thr 1.39e-2).
// ---------------------------------------------------------------------------
__global__ __launch_bounds__(128) void k_gating(
    const float* __restrict__ mid, const float* __restrict__ w_gate,
    float* __restrict__ gates_ws, float* __restrict__ moe_out)
{
  __shared__ float lg[BB][NEXP];
  __shared__ float gt[BB][NEXP];
  int t = threadIdx.x;
  {
    int b = t >> 3, e = t & 7;
    float acc = 0.f;
    #pragma unroll 8
    for (int k = 0; k < ED; ++k) acc += mid[b*ED + k] * w_gate[k*NEXP + e];
    lg[b][e] = acc;
  }
  __syncthreads();
  if (t < BB) {
    int b = t;
    int i1 = 0; float v1 = lg[b][0];
    #pragma unroll
    for (int e = 1; e < NEXP; ++e) if (lg[b][e] > v1) { v1 = lg[b][e]; i1 = e; }
    int i2 = -1; float v2 = -3.0e38f;
    #pragma unroll
    for (int e = 0; e < NEXP; ++e) if (e != i1 && lg[b][e] > v2) { v2 = lg[b][e]; i2 = e; }
    float e2 = __expf(v2 - v1);          // <= 1
    float g1 = 1.f / (1.f + e2);
    #pragma unroll
    for (int e = 0; e < NEXP; ++e) gt[b][e] = 0.f;
    gt[b][i1] = g1;
    gt[b][i2] = e2 * g1;
  }
  __syncthreads();
  if (t < BB*NEXP) gates_ws[t] = gt[t >> 3][t & 7];
  if (t == 0) {
    float imp[NEXP], ldc[NEXP];
    #pragma unroll
    for (int e = 0; e < NEXP; ++e) { imp[e] = 0.f; ldc[e] = 0.f; }
    for (int b = 0; b < BB; ++b)
      #pragma unroll
      for (int e = 0; e < NEXP; ++e) {
        float g = gt[b][e];
        imp[e] += g;
        if (g > 0.f) ldc[e] += 1.f;
      }
    float im = 0.f, lm = 0.f;
    #pragma unroll
    for (int e = 0; e < NEXP; ++e) { im += imp[e]; lm += ldc[e]; }
    im *= 0.125f; lm *= 0.125f;
    float iv = 0.f, lv = 0.f;
    #pragma unroll
    for (int e = 0; e < NEXP; ++e) {
      float a = imp[e] - im; iv += a*a;
      float c = ldc[e] - lm; lv += c*c;
    }
    iv *= 0.125f; lv *= 0.125f;
    moe_out[0] = iv / (im*im + 1e-10f) + lv / (lm*lm + 1e-10f);
  }
}

// ---------------------------------------------------------------------------
// K2 v3: WCh[b] = f16 (k,k+1)-pairs of sum_e g_e*expert_W[e]; BC fp32.
// ---------------------------------------------------------------------------
__global__ __launch_bounds__(256) void k_experts(
    const float* __restrict__ gates, const float* __restrict__ eW,
    const float* __restrict__ eB, float* __restrict__ WCh, float* __restrict__ BC)
{
  __shared__ float g[NEXP];
  int tid = threadIdx.x;
  int b = blockIdx.x >> 3;
  int tile = blockIdx.x & 7;           // 8 tiles of 1024 packed floats
  if (tid < NEXP) g[tid] = gates[b*NEXP + tid];
  __syncthreads();
  int i0 = tile * 1024;
  #pragma unroll
  for (int j = 0; j < 4; ++j) {
    int pi = i0 + tid + j*256;         // packed index: p*128 + c
    int k2 = (pi >> 7) << 1;           // 2p
    int c  = pi & 127;
    float a0 = 0.f, a1 = 0.f;
    #pragma unroll
    for (int e = 0; e < NEXP; ++e) {
      a0 += g[e] * eW[e*ED*ED + k2*ED + c];
      a1 += g[e] * eW[e*ED*ED + (k2+1)*ED + c];
    }
    WCh[(size_t)b*8192 + pi] = packh2(a0, a1);
  }
  if (tile == 0 && tid < ED) {
    float a = 0.f;
    #pragma unroll
    for (int e = 0; e < NEXP; ++e) a += g[e] * eB[e*ED + tid];
    BC[b*ED + tid] = a;
  }
}

// ---------------------------------------------------------------------------
// K3 v4: K/V projection with f16 fdot2 inner loop (R10 proven).
// ---------------------------------------------------------------------------
__global__ __launch_bounds__(256) void k_kv(
    const float* __restrict__ nodes, const float* __restrict__ Wk,
    const float* __restrict__ Wv, float* __restrict__ Khf,
    float* __restrict__ VhTf, float* __restrict__ Nhf)
{
  __shared__ __align__(16) float Ash[64*66];     // 64 rows x (64 d-pairs + 2 pad)
  __shared__ __align__(16) float Wkp[16*128];    // f16 pairs [p][c]
  __shared__ __align__(16) float Wvp[16*128];
  int tid = threadIdx.x;
  int r0 = blockIdx.x * 64;
  #pragma unroll
  for (int j = 0; j < 8; ++j) {
    int idx = tid + j*256;
    int row = idx >> 5, c4 = (idx & 31) << 2;
    float4 v = *(const float4*)&nodes[(size_t)(r0 + row)*ED + c4];
    float2 nh; nh.x = packh2(v.x, v.y); nh.y = packh2(v.z, v.w);
    *(float2*)&Ash[row*66 + (c4 >> 1)] = nh;
    *(float2*)&Nhf[(size_t)(r0 + row)*64 + (c4 >> 1)] = nh;
  }
  int colg = tid & 15, rowg = tid >> 4;
  int c0 = colg << 2;              // cols c0..c0+3 and c0+64..c0+67
  float accK[4][8], accV[4][8];
  #pragma unroll
  for (int i = 0; i < 4; ++i)
    #pragma unroll
    for (int j = 0; j < 8; ++j) { accK[i][j] = 0.f; accV[i][j] = 0.f; }

  for (int kk = 0; kk < 128; kk += 32) {
    __syncthreads();
    #pragma unroll
    for (int j = 0; j < 2; ++j) {
      int wi = tid + j*256;
      int p = wi >> 5, c4 = (wi & 31) << 2;
      float4 ka = *(const float4*)&Wk[(kk + 2*p)*ED + c4];
      float4 kb = *(const float4*)&Wk[(kk + 2*p + 1)*ED + c4];
      float4 pk; pk.x = packh2(ka.x, kb.x); pk.y = packh2(ka.y, kb.y);
      pk.z = packh2(ka.z, kb.z); pk.w = packh2(ka.w, kb.w);
      *(float4*)&Wkp[p*128 + c4] = pk;
      float4 va = *(const float4*)&Wv[(kk + 2*p)*ED + c4];
      float4 vb = *(const float4*)&Wv[(kk + 2*p + 1)*ED + c4];
      float4 pv; pv.x = packh2(va.x, vb.x); pv.y = packh2(va.y, vb.y);
      pv.z = packh2(va.z, vb.z); pv.w = packh2(va.w, vb.w);
      *(float4*)&Wvp[p*128 + c4] = pv;
    }
    __syncthreads();
    #pragma unroll 4
    for (int p = 0; p < 16; ++p) {
      float ap[4];
      #pragma unroll
      for (int i = 0; i < 4; ++i) ap[i] = Ash[(rowg*4 + i)*66 + (kk >> 1) + p];
      float4 wk0 = *(float4*)&Wkp[p*128 + c0];
      float4 wk1 = *(float4*)&Wkp[p*128 + c0 + 64];
      float4 wv0 = *(float4*)&Wvp[p*128 + c0];
      float4 wv1 = *(float4*)&Wvp[p*128 + c0 + 64];
      #pragma unroll
      for (int i = 0; i < 4; ++i) {
        f16x2 ai = f2h(ap[i]);
        accK[i][0] = fdot2f(ai, f2h(wk0.x), accK[i][0]);
        accK[i][1] = fdot2f(ai, f2h(wk0.y), accK[i][1]);
        accK[i][2] = fdot2f(ai, f2h(wk0.z), accK[i][2]);
        accK[i][3] = fdot2f(ai, f2h(wk0.w), accK[i][3]);
        accK[i][4] = fdot2f(ai, f2h(wk1.x), accK[i][4]);
        accK[i][5] = fdot2f(ai, f2h(wk1.y), accK[i][5]);
        accK[i][6] = fdot2f(ai, f2h(wk1.z), accK[i][6]);
        accK[i][7] = fdot2f(ai, f2h(wk1.w), accK[i][7]);
        accV[i][0] = fdot2f(ai, f2h(wv0.x), accV[i][0]);
        accV[i][1] = fdot2f(ai, f2h(wv0.y), accV[i][1]);
        accV[i][2] = fdot2f(ai, f2h(wv0.z), accV[i][2]);
        accV[i][3] = fdot2f(ai, f2h(wv0.w), accV[i][3]);
        accV[i][4] = fdot2f(ai, f2h(wv1.x), accV[i][4]);
        accV[i][5] = fdot2f(ai, f2h(wv1.y), accV[i][5]);
        accV[i][6] = fdot2f(ai, f2h(wv1.z), accV[i][6]);
        accV[i][7] = fdot2f(ai, f2h(wv1.w), accV[i][7]);
      }
    }
  }
  // K: f16 row-major
  #pragma unroll
  for (int i = 0; i < 4; ++i) {
    size_t row = (size_t)(r0 + rowg*4 + i);
    float2 k0; k0.x = packh2(accK[i][0], accK[i][1]); k0.y = packh2(accK[i][2], accK[i][3]);
    float2 k1; k1.x = packh2(accK[i][4], accK[i][5]); k1.y = packh2(accK[i][6], accK[i][7]);
    *(float2*)&Khf[row*64 + (c0 >> 1)]      = k0;
    *(float2*)&Khf[row*64 + (c0 >> 1) + 32] = k1;
  }
  // V: f16 transposed [b][col][n] — thread's 4 rows are consecutive n
  int bb = r0 >> 11;
  int nn0 = (r0 & 2047) + rowg*4;
  #pragma unroll
  for (int j = 0; j < 8; ++j) {
    int col = (j < 4) ? (c0 + j) : (c0 + 60 + j);
    float2 vv; vv.x = packh2(accV[0][j], accV[1][j]); vv.y = packh2(accV[2][j], accV[3][j]);
    *(float2*)&VhTf[((size_t)bb*128 + col)*1024 + (nn0 >> 1)] = vv;
  }
}

// ---------------------------------------------------------------------------
// K4: Q = [last, load] @ Wq_last, fp32 compute, f16 output (R9 proven)
// ---------------------------------------------------------------------------
__global__ __launch_bounds__(256) void k_q(
    const float* __restrict__ last, const float* __restrict__ loadv,
    const float* __restrict__ Wq, float* __restrict__ Qhf)
{
  __shared__ __align__(16) float As[32*132];
  __shared__ __align__(16) float Ws[129*128];
  int tid = threadIdx.x;
  int r0 = blockIdx.x * 32;
  #pragma unroll
  for (int j = 0; j < 4; ++j) {
    int idx = tid + j*256;
    int row = idx >> 5, c4 = (idx & 31) << 2;
    *(float4*)&As[row*132 + c4] = *(const float4*)&last[(size_t)(r0 + row)*ED + c4];
  }
  if (tid < 32) As[tid*132 + 128] = loadv[r0 + tid];
  for (int idx = tid; idx < 4128; idx += 256)
    *(float4*)&Ws[idx*4] = *(const float4*)&Wq[idx*4];
  __syncthreads();

  int colg = tid & 15, rowg = tid >> 4;
  int c0 = colg << 2;
  float acc[2][8];
  #pragma unroll
  for (int i = 0; i < 2; ++i)
    #pragma unroll
    for (int j = 0; j < 8; ++j) acc[i][j] = 0.f;
  #pragma unroll 4
  for (int k = 0; k < 129; ++k) {
    float a0 = As[(rowg*2)*132 + k];
    float a1 = As[(rowg*2 + 1)*132 + k];
    float4 w0 = *(float4*)&Ws[k*128 + c0];
    float4 w1 = *(float4*)&Ws[k*128 + c0 + 64];
    acc[0][0] += a0*w0.x; acc[0][1] += a0*w0.y; acc[0][2] += a0*w0.z; acc[0][3] += a0*w0.w;
    acc[0][4] += a0*w1.x; acc[0][5] += a0*w1.y; acc[0][6] += a0*w1.z; acc[0][7] += a0*w1.w;
    acc[1][0] += a1*w0.x; acc[1][1] += a1*w0.y; acc[1][2] += a1*w0.z; acc[1][3] += a1*w0.w;
    acc[1][4] += a1*w1.x; acc[1][5] += a1*w1.y; acc[1][6] += a1*w1.z; acc[1][7] += a1*w1.w;
  }
  #pragma unroll
  for (int i = 0; i < 2; ++i) {
    size_t row = (size_t)(r0 + rowg*2 + i);
    float2 q0; q0.x = packh2(acc[i][0], acc[i][1]); q0.y = packh2(acc[i][2], acc[i][3]);
    float2 q1; q1.x = packh2(acc[i][4], acc[i][5]); q1.y = packh2(acc[i][6], acc[i][7]);
    *(float2*)&Qhf[row*64 + (c0 >> 1)]      = q0;
    *(float2*)&Qhf[row*64 + (c0 >> 1) + 32] = q1;
  }
}

// ---------------------------------------------------------------------------
// K5 v9: R10's f16 attention with 1 query/thread, ph 8->16, grid (128,16)
// = 2048 blocks = 8 blocks/CU (was 4), launch_bounds(256,8).
// Per-thread live state HALVES vs the proven R9/R10 config (q[8]+acc[16]+
// m,l,s[8]) -> VGPR ~48-56, no spill risk. Inner-loop structure unchanged.
// DO NOT add: reg prefetch, vectorized mask map, defer-max, bigger KVBLK
// (R2/R4/R5/R7 all spilled). Guard: WRITE_SIZE KB-scale, VGPR <= 64.
// ---------------------------------------------------------------------------
__global__ __launch_bounds__(256, 8) void k_attn(
    const float* __restrict__ Khf, const float* __restrict__ VhTf,
    const float* __restrict__ Qhf, const float* __restrict__ mask,
    float* __restrict__ Oph)
{
  __shared__ __align__(16) float kt[64*20];   // 64 key-pairs x (32 halfs + pad)
  __shared__ __align__(16) float vt[16*68];   // 16 d-rows x (128 key halfs + pad)
  int tid = threadIdx.x;
  int h = blockIdx.x & 7, b = blockIdx.x >> 3;
  int ph = blockIdx.y;
  int nq = tid & 15;
  int pg = tid >> 4;
  int prow0 = b*POMO + ph*16 + pg;            // 16 queries/block, 1/thread-group
  const float* maskb = mask + (size_t)prow0 * PROBN;
  const float* Kb = Khf + (size_t)b*PROBN*64 + h*8;        // float units
  const float* Vb = VhTf + ((size_t)b*128 + h*16)*1024;    // d-row stride 1024 floats

  f16x2 q[8];
  {
    const float* qp = Qhf + (size_t)prow0*64 + h*8;
    float4 t0 = *(const float4*)&qp[0];
    float4 t1 = *(const float4*)&qp[4];
    q[0] = f2h(t0.x); q[1] = f2h(t0.y); q[2] = f2h(t0.z); q[3] = f2h(t0.w);
    q[4] = f2h(t1.x); q[5] = f2h(t1.y); q[6] = f2h(t1.z); q[7] = f2h(t1.w);
  }
  float m = -1.0e30f, l = 0.f, acc[16];
  #pragma unroll
  for (int dd = 0; dd < 16; ++dd) acc[dd] = 0.f;

  int srow = tid >> 1, part = tid & 1;                  // K staging: 2 thr/row
  int kws = 20*(srow >> 1) + 8*(srow & 1) + 4*part;
  int vrow = tid >> 4, vchunk = tid & 15;               // V^T staging
  int vws = 68*vrow + 4*vchunk;

  for (int tile = 0; tile < 16; ++tile) {
    int t0 = tile << 7;
    if (tile > 0) __syncthreads();
    *(float4*)&kt[kws] = *(const float4*)&Kb[(size_t)(t0 + srow)*64 + part*4];
    *(float4*)&vt[vws] = *(const float4*)&Vb[(size_t)vrow*1024 + (t0 >> 1) + vchunk*4];
    __syncthreads();

    // ---- scores (scalar mask loads, R6 style) ----
    float s[8];
    #pragma unroll
    for (int i = 0; i < 4; ++i) {
      s[2*i]   = maskb[t0 + 2*nq + 32*i];
      s[2*i+1] = maskb[t0 + 2*nq + 32*i + 1];
    }
    #pragma unroll
    for (int i = 0; i < 4; ++i) {
      int p = nq + 16*i;
      float4 a0 = *(float4*)&kt[20*p];
      float4 a1 = *(float4*)&kt[20*p + 4];
      float4 b0 = *(float4*)&kt[20*p + 8];
      float4 b1 = *(float4*)&kt[20*p + 12];
      f16x2 ka[8] = {f2h(a0.x), f2h(a0.y), f2h(a0.z), f2h(a0.w),
                     f2h(a1.x), f2h(a1.y), f2h(a1.z), f2h(a1.w)};
      f16x2 kb[8] = {f2h(b0.x), f2h(b0.y), f2h(b0.z), f2h(b0.w),
                     f2h(b1.x), f2h(b1.y), f2h(b1.z), f2h(b1.w)};
      float d0 = 0.f, d1 = 0.f;
      #pragma unroll
      for (int j = 0; j < 8; ++j) {
        d0 = fdot2f(q[j], ka[j], d0);
        d1 = fdot2f(q[j], kb[j], d1);
      }
      s[2*i]   += d0 * 0.25f;
      s[2*i+1] += d1 * 0.25f;
    }
    // ---- per-tile max merge + single unconditional rescale ----
    {
      float tm = s[0];
      #pragma unroll
      for (int i = 1; i < 8; ++i) tm = fmaxf(tm, s[i]);
      float M = fmaxf(m, tm);
      float c = __expf(m - M);
      m = M;
      l *= c;
      #pragma unroll
      for (int dd = 0; dd < 16; ++dd) acc[dd] *= c;
    }
    // ---- exp + PV (pairwise fdot2 into fp32 acc) ----
    #pragma unroll
    for (int i = 0; i < 4; ++i) {
      int p = nq + 16*i;
      f16x2 wp;
      {
        float w0 = __expf(s[2*i] - m);
        float w1 = __expf(s[2*i+1] - m);
        l += w0 + w1;
        wp.x = (f16)w0; wp.y = (f16)w1;
      }
      #pragma unroll
      for (int dd = 0; dd < 16; ++dd) {
        f16x2 vh = f2h(vt[68*dd + p]);
        acc[dd] = fdot2f(wp, vh, acc[dd]);
      }
    }
  }

  // merge 16 stripes (tid bits 0..3, within wave)
  #pragma unroll
  for (int off = 1; off < 16; off <<= 1) {
    float m2 = __shfl_xor(m, off);
    float l2 = __shfl_xor(l, off);
    float M = fmaxf(m, m2);
    float c1 = __expf(m - M), c2 = __expf(m2 - M);
    l = l*c1 + l2*c2;
    m = M;
    #pragma unroll
    for (int dd = 0; dd < 16; ++dd) {
      float a2 = __shfl_xor(acc[dd], off);
      acc[dd] = acc[dd]*c1 + a2*c2;
    }
  }
  // write f16-packed: lanes nq<4, compile-time indexed (rule #20)
  #pragma unroll
  for (int d4 = 0; d4 < 4; ++d4) {
    if (nq == d4) {
      float rl = 1.f / l;
      float2 o;
      o.x = packh2(acc[4*d4+0]*rl, acc[4*d4+1]*rl);
      o.y = packh2(acc[4*d4+2]*rl, acc[4*d4+3]*rl);
      *(float2*)&Oph[(size_t)prow0*64 + h*8 + d4*2] = o;
    }
  }
}

// ---------------------------------------------------------------------------
// K6 v3: MH = Oph @ WCh[b] + BC[b], f16 fdot2, grid 256 (R10 proven).
// ---------------------------------------------------------------------------
__global__ __launch_bounds__(256) void k_mh(
    const float* __restrict__ Oph, const float* __restrict__ WCh,
    const float* __restrict__ BC, float* __restrict__ MH)
{
  __shared__ __align__(16) float Ash[16*66];    // 16 rows x 64 d-pairs (+pad)
  __shared__ __align__(16) float Wp[64*128];    // 32KB f16 pairs [p][c]
  int tid = threadIdx.x;
  int b = blockIdx.x >> 4;
  int pt = blockIdx.x & 15;
  int r0 = b*POMO + pt*16;
  {
    int row = tid >> 4, c4 = (tid & 15) << 2;
    *(float4*)&Ash[row*66 + c4] = *(const float4*)&Oph[(size_t)(r0 + row)*64 + c4];
  }
  #pragma unroll
  for (int j = 0; j < 8; ++j) {
    int wi = tid + j*256;
    *(float4*)&Wp[wi*4] = *(const float4*)&WCh[(size_t)b*8192 + wi*4];
  }
  __syncthreads();

  int colg = tid & 15, rowg = tid >> 4;
  int c0 = colg << 2;
  float4 b0 = *(const float4*)&BC[b*ED + c0];
  float4 b1 = *(const float4*)&BC[b*ED + c0 + 64];
  float acc[8] = {b0.x, b0.y, b0.z, b0.w, b1.x, b1.y, b1.z, b1.w};
  #pragma unroll 4
  for (int p = 0; p < 64; ++p) {
    f16x2 a = f2h(Ash[rowg*66 + p]);
    float4 w0 = *(float4*)&Wp[p*128 + c0];
    float4 w1 = *(float4*)&Wp[p*128 + c0 + 64];
    acc[0] = fdot2f(a, f2h(w0.x), acc[0]);
    acc[1] = fdot2f(a, f2h(w0.y), acc[1]);
    acc[2] = fdot2f(a, f2h(w0.z), acc[2]);
    acc[3] = fdot2f(a, f2h(w0.w), acc[3]);
    acc[4] = fdot2f(a, f2h(w1.x), acc[4]);
    acc[5] = fdot2f(a, f2h(w1.y), acc[5]);
    acc[6] = fdot2f(a, f2h(w1.z), acc[6]);
    acc[7] = fdot2f(a, f2h(w1.w), acc[7]);
  }
  size_t row = (size_t)(r0 + rowg) * ED;
  *(float4*)&MH[row + c0]      = make_float4(acc[0], acc[1], acc[2], acc[3]);
  *(float4*)&MH[row + c0 + 64] = make_float4(acc[4], acc[5], acc[6], acc[7]);
}

// ---------------------------------------------------------------------------
// K7 v4: score2 = MH @ nodes^T / sqrt(E) via f16 fdot2; probs = softmax.
// Split 8->4 p-rows/block (grid 1024): lg 32KB -> 4-5 blocks/CU (was 2);
// phase 2: wave w owns exactly p-row w.
// ---------------------------------------------------------------------------
__global__ __launch_bounds__(256) void k_final(
    const float* __restrict__ MH, const float* __restrict__ Nhf,
    const float* __restrict__ mask, float* __restrict__ probs)
{
  __shared__ __align__(16) float lg[4*PROBN];     // 32 KB
  __shared__ __align__(16) float mh8[4*68];       // f16 MH rows
  int tid = threadIdx.x;
  int b = blockIdx.x >> 6;
  int p0 = (blockIdx.x & 63) * 4;
  if (tid < 128) {
    int row = tid >> 5, c4 = (tid & 31) << 2;
    float4 v = *(const float4*)&MH[(size_t)(b*POMO + p0 + row)*ED + c4];
    float2 hh; hh.x = packh2(v.x, v.y); hh.y = packh2(v.z, v.w);
    *(float2*)&mh8[row*68 + (c4 >> 1)] = hh;
  }
  __syncthreads();
  const float invs = 0.08838834764831845f;        // 1/sqrt(128)
  #pragma unroll
  for (int j = 0; j < 8; ++j) {
    int n = tid + (j << 8);
    const float* nr = &Nhf[(size_t)(b*PROBN + n)*64];
    float a[4];
    #pragma unroll
    for (int p = 0; p < 4; ++p) a[p] = 0.f;
    #pragma unroll 4
    for (int kq = 0; kq < 16; ++kq) {
      float4 nv = *(const float4*)&nr[kq*4];
      f16x2 n0 = f2h(nv.x), n1 = f2h(nv.y), n2 = f2h(nv.z), n3 = f2h(nv.w);
      #pragma unroll
      for (int p = 0; p < 4; ++p) {
        float4 mv = *(const float4*)&mh8[p*68 + kq*4];
        a[p] = fdot2f(f2h(mv.x), n0, a[p]);
        a[p] = fdot2f(f2h(mv.y), n1, a[p]);
        a[p] = fdot2f(f2h(mv.z), n2, a[p]);
        a[p] = fdot2f(f2h(mv.w), n3, a[p]);
      }
    }
    #pragma unroll
    for (int p = 0; p < 4; ++p) lg[p*PROBN + n] = a[p] * invs;
  }
  __syncthreads();

  int wid = tid >> 6, lane = tid & 63;
  {
    int p = wid;
    const float* mrow = mask + (size_t)(b*POMO + p0 + p) * PROBN;
    float* prow = probs + (size_t)(b*POMO + p0 + p) * PROBN;
    float z[32];
    float mx = -3.0e38f;
    #pragma unroll
    for (int i4 = 0; i4 < 8; ++i4) {
      int n = 4*lane + 256*i4;
      float4 lv = *(const float4*)&lg[p*PROBN + n];
      float4 mv = *(const float4*)&mrow[n];
      float z0 = 10.f - 20.f/(__expf(2.f*lv.x)+1.f) + mv.x;
      float z1 = 10.f - 20.f/(__expf(2.f*lv.y)+1.f) + mv.y;
      float z2 = 10.f - 20.f/(__expf(2.f*lv.z)+1.f) + mv.z;
      float z3 = 10.f - 20.f/(__expf(2.f*lv.w)+1.f) + mv.w;
      z[4*i4+0] = z0; z[4*i4+1] = z1; z[4*i4+2] = z2; z[4*i4+3] = z3;
      mx = fmaxf(fmaxf(fmaxf(mx, z0), fmaxf(z1, z2)), z3);
    }
    #pragma unroll
    for (int off = 32; off > 0; off >>= 1) mx = fmaxf(mx, __shfl_xor(mx, off));
    float sum = 0.f;
    #pragma unroll
    for (int k = 0; k < 32; ++k) { z[k] = __expf(z[k] - mx); sum += z[k]; }
    #pragma unroll
    for (int off = 32; off > 0; off >>= 1) sum += __shfl_xor(sum, off);
    float rs = 1.f / sum;
    #pragma unroll
    for (int i4 = 0; i4 < 8; ++i4) {
      int n = 4*lane + 256*i4;
      *(float4*)&prow[n] = make_float4(z[4*i4+0]*rs, z[4*i4+1]*rs,
                                       z[4*i4+2]*rs, z[4*i4+3]*rs);
    }
  }
}

// ---------------------------------------------------------------------------
extern "C" void kernel_launch(void* const* d_in, const int* in_sizes, int n_in,
                              void* d_out, int out_size, void* d_ws, size_t ws_size,
                              hipStream_t stream)
{
  const float* nodes  = (const float*)d_in[0];
  const float* last   = (const float*)d_in[1];
  const float* mid    = (const float*)d_in[2];
  const float* loadv  = (const float*)d_in[3];
  const float* mask   = (const float*)d_in[4];
  const float* Wq     = (const float*)d_in[5];
  const float* Wk     = (const float*)d_in[6];
  const float* Wv     = (const float*)d_in[7];
  const float* eW     = (const float*)d_in[8];
  const float* eB     = (const float*)d_in[9];
  const float* w_gate = (const float*)d_in[10];
  float* out = (float*)d_out;
  float* ws  = (float*)d_ws;

  k_gating<<<1, 128, 0, stream>>>(mid, w_gate, ws + WS_GATES, out + BB*POMO*PROBN);
  k_experts<<<128, 256, 0, stream>>>(ws + WS_GATES, eW, eB, ws + WS_WC, ws + WS_BC);
  k_kv<<<512, 256, 0, stream>>>(nodes, Wk, Wv, ws + WS_KH, ws + WS_VHT, ws + WS_NH);
  k_q<<<128, 256, 0, stream>>>(last, loadv, Wq, ws + WS_QH);
  k_attn<<<dim3(128, 16), 256, 0, stream>>>(ws + WS_KH, ws + WS_VHT, ws + WS_QH, mask, ws + WS_OUT);
  k_mh<<<256, 256, 0, stream>>>(ws + WS_OUT, ws + WS_WC, ws + WS_BC, ws + WS_MH);
  k_final<<<1024, 256, 0, stream>>>(ws + WS_MH, ws + WS_NH, mask, out);
}

// Round 12
// 187.783 us; speedup vs baseline: 1.1928x; 1.1928x over previous
//
#include <hip/hip_runtime.h>
#include <math.h>

#define BB    16
#define PROBN 2048
#define POMO  256
#define ED    128
#define HN    8
#define DDIM  16
#define NEXP  8

typedef _Float16 f16;
typedef f16 f16x2 __attribute__((ext_vector_type(2)));

__device__ __forceinline__ f16x2 f2h(float f) {
  union U { float f; f16x2 h; } u; u.f = f; return u.h;
}
__device__ __forceinline__ float packh2(float a, float b) {
  union U { float f; f16x2 h; } u; u.h.x = (f16)a; u.h.y = (f16)b; return u.f;
}
__device__ __forceinline__ float fdot2f(f16x2 a, f16x2 b, float c) {
#if __has_builtin(__builtin_amdgcn_fdot2)
  return __builtin_amdgcn_fdot2(a, b, c, false);
#else
  return c + (float)a.x * (float)b.x + (float)a.y * (float)b.y;
#endif
}

// ws float offsets (f16 arrays addressed as float*)
#define WS_KH    0                        // f16 K [b][n][h*16+d]    (2,097,152 floats)
#define WS_VHT   (WS_KH + 2097152)        // f16 V^T [b][h*16+d][n]  (2,097,152)
#define WS_NH    (WS_VHT + 2097152)       // f16 nodes [b][n][d]     (2,097,152)
#define WS_QH    (WS_NH + 2097152)        // f16 Q [b*POMO][d]       (262,144)
#define WS_OUT   (WS_QH + 262144)         // f16 attn out [row][64f] (262,144)
#define WS_MH    (WS_OUT + 262144)        // fp32 MoE out            (524,288)
#define WS_WC    (WS_MH + 524288)         // f16 WC pairs [b][p][c]  (131,072)
#define WS_BC    (WS_WC + 131072)         // fp32 combined bias      (2,048)
#define WS_GATES (WS_BC + 2048)           // fp32 gates              (128)
#define WS_PART  (WS_GATES + 128)         // fp32 attn partials      (1,310,720)
                                          // [r(4096)][h(8)][z(2)] x 20 floats

// ---------------------------------------------------------------------------
// K1: gating (top-2 softmax), gates -> ws, moe_loss -> d_out tail. FP32-EXACT.
// ---------------------------------------------------------------------------
__global__ __launch_bounds__(128) void k_gating(
    const float* __restrict__ mid, const float* __restrict__ w_gate,
    float* __restrict__ gates_ws, float* __restrict__ moe_out)
{
  __shared__ float lg[BB][NEXP];
  __shared__ float gt[BB][NEXP];
  int t = threadIdx.x;
  {
    int b = t >> 3, e = t & 7;
    float acc = 0.f;
    #pragma unroll 8
    for (int k = 0; k < ED; ++k) acc += mid[b*ED + k] * w_gate[k*NEXP + e];
    lg[b][e] = acc;
  }
  __syncthreads();
  if (t < BB) {
    int b = t;
    int i1 = 0; float v1 = lg[b][0];
    #pragma unroll
    for (int e = 1; e < NEXP; ++e) if (lg[b][e] > v1) { v1 = lg[b][e]; i1 = e; }
    int i2 = -1; float v2 = -3.0e38f;
    #pragma unroll
    for (int e = 0; e < NEXP; ++e) if (e != i1 && lg[b][e] > v2) { v2 = lg[b][e]; i2 = e; }
    float e2 = __expf(v2 - v1);          // <= 1
    float g1 = 1.f / (1.f + e2);
    #pragma unroll
    for (int e = 0; e < NEXP; ++e) gt[b][e] = 0.f;
    gt[b][i1] = g1;
    gt[b][i2] = e2 * g1;
  }
  __syncthreads();
  if (t < BB*NEXP) gates_ws[t] = gt[t >> 3][t & 7];
  if (t == 0) {
    float imp[NEXP], ldc[NEXP];
    #pragma unroll
    for (int e = 0; e < NEXP; ++e) { imp[e] = 0.f; ldc[e] = 0.f; }
    for (int b = 0; b < BB; ++b)
      #pragma unroll
      for (int e = 0; e < NEXP; ++e) {
        float g = gt[b][e];
        imp[e] += g;
        if (g > 0.f) ldc[e] += 1.f;
      }
    float im = 0.f, lm = 0.f;
    #pragma unroll
    for (int e = 0; e < NEXP; ++e) { im += imp[e]; lm += ldc[e]; }
    im *= 0.125f; lm *= 0.125f;
    float iv = 0.f, lv = 0.f;
    #pragma unroll
    for (int e = 0; e < NEXP; ++e) {
      float a = imp[e] - im; iv += a*a;
      float c = ldc[e] - lm; lv += c*c;
    }
    iv *= 0.125f; lv *= 0.125f;
    moe_out[0] = iv / (im*im + 1e-10f) + lv / (lm*lm + 1e-10f);
  }
}

// ---------------------------------------------------------------------------
// K2 v3: WCh[b] = f16 (k,k+1)-pairs of sum_e g_e*expert_W[e]; BC fp32.
// ---------------------------------------------------------------------------
__global__ __launch_bounds__(256) void k_experts(
    const float* __restrict__ gates, const float* __restrict__ eW,
    const float* __restrict__ eB, float* __restrict__ WCh, float* __restrict__ BC)
{
  __shared__ float g[NEXP];
  int tid = threadIdx.x;
  int b = blockIdx.x >> 3;
  int tile = blockIdx.x & 7;           // 8 tiles of 1024 packed floats
  if (tid < NEXP) g[tid] = gates[b*NEXP + tid];
  __syncthreads();
  int i0 = tile * 1024;
  #pragma unroll
  for (int j = 0; j < 4; ++j) {
    int pi = i0 + tid + j*256;         // packed index: p*128 + c
    int k2 = (pi >> 7) << 1;           // 2p
    int c  = pi & 127;
    float a0 = 0.f, a1 = 0.f;
    #pragma unroll
    for (int e = 0; e < NEXP; ++e) {
      a0 += g[e] * eW[e*ED*ED + k2*ED + c];
      a1 += g[e] * eW[e*ED*ED + (k2+1)*ED + c];
    }
    WCh[(size_t)b*8192 + pi] = packh2(a0, a1);
  }
  if (tile == 0 && tid < ED) {
    float a = 0.f;
    #pragma unroll
    for (int e = 0; e < NEXP; ++e) a += g[e] * eB[e*ED + tid];
    BC[b*ED + tid] = a;
  }
}

// ---------------------------------------------------------------------------
// K3 v4: K/V projection with f16 fdot2 inner loop (R10 proven).
// ---------------------------------------------------------------------------
__global__ __launch_bounds__(256) void k_kv(
    const float* __restrict__ nodes, const float* __restrict__ Wk,
    const float* __restrict__ Wv, float* __restrict__ Khf,
    float* __restrict__ VhTf, float* __restrict__ Nhf)
{
  __shared__ __align__(16) float Ash[64*66];     // 64 rows x (64 d-pairs + 2 pad)
  __shared__ __align__(16) float Wkp[16*128];    // f16 pairs [p][c]
  __shared__ __align__(16) float Wvp[16*128];
  int tid = threadIdx.x;
  int r0 = blockIdx.x * 64;
  #pragma unroll
  for (int j = 0; j < 8; ++j) {
    int idx = tid + j*256;
    int row = idx >> 5, c4 = (idx & 31) << 2;
    float4 v = *(const float4*)&nodes[(size_t)(r0 + row)*ED + c4];
    float2 nh; nh.x = packh2(v.x, v.y); nh.y = packh2(v.z, v.w);
    *(float2*)&Ash[row*66 + (c4 >> 1)] = nh;
    *(float2*)&Nhf[(size_t)(r0 + row)*64 + (c4 >> 1)] = nh;
  }
  int colg = tid & 15, rowg = tid >> 4;
  int c0 = colg << 2;              // cols c0..c0+3 and c0+64..c0+67
  float accK[4][8], accV[4][8];
  #pragma unroll
  for (int i = 0; i < 4; ++i)
    #pragma unroll
    for (int j = 0; j < 8; ++j) { accK[i][j] = 0.f; accV[i][j] = 0.f; }

  for (int kk = 0; kk < 128; kk += 32) {
    __syncthreads();
    #pragma unroll
    for (int j = 0; j < 2; ++j) {
      int wi = tid + j*256;
      int p = wi >> 5, c4 = (wi & 31) << 2;
      float4 ka = *(const float4*)&Wk[(kk + 2*p)*ED + c4];
      float4 kb = *(const float4*)&Wk[(kk + 2*p + 1)*ED + c4];
      float4 pk; pk.x = packh2(ka.x, kb.x); pk.y = packh2(ka.y, kb.y);
      pk.z = packh2(ka.z, kb.z); pk.w = packh2(ka.w, kb.w);
      *(float4*)&Wkp[p*128 + c4] = pk;
      float4 va = *(const float4*)&Wv[(kk + 2*p)*ED + c4];
      float4 vb = *(const float4*)&Wv[(kk + 2*p + 1)*ED + c4];
      float4 pv; pv.x = packh2(va.x, vb.x); pv.y = packh2(va.y, vb.y);
      pv.z = packh2(va.z, vb.z); pv.w = packh2(va.w, vb.w);
      *(float4*)&Wvp[p*128 + c4] = pv;
    }
    __syncthreads();
    #pragma unroll 4
    for (int p = 0; p < 16; ++p) {
      float ap[4];
      #pragma unroll
      for (int i = 0; i < 4; ++i) ap[i] = Ash[(rowg*4 + i)*66 + (kk >> 1) + p];
      float4 wk0 = *(float4*)&Wkp[p*128 + c0];
      float4 wk1 = *(float4*)&Wkp[p*128 + c0 + 64];
      float4 wv0 = *(float4*)&Wvp[p*128 + c0];
      float4 wv1 = *(float4*)&Wvp[p*128 + c0 + 64];
      #pragma unroll
      for (int i = 0; i < 4; ++i) {
        f16x2 ai = f2h(ap[i]);
        accK[i][0] = fdot2f(ai, f2h(wk0.x), accK[i][0]);
        accK[i][1] = fdot2f(ai, f2h(wk0.y), accK[i][1]);
        accK[i][2] = fdot2f(ai, f2h(wk0.z), accK[i][2]);
        accK[i][3] = fdot2f(ai, f2h(wk0.w), accK[i][3]);
        accK[i][4] = fdot2f(ai, f2h(wk1.x), accK[i][4]);
        accK[i][5] = fdot2f(ai, f2h(wk1.y), accK[i][5]);
        accK[i][6] = fdot2f(ai, f2h(wk1.z), accK[i][6]);
        accK[i][7] = fdot2f(ai, f2h(wk1.w), accK[i][7]);
        accV[i][0] = fdot2f(ai, f2h(wv0.x), accV[i][0]);
        accV[i][1] = fdot2f(ai, f2h(wv0.y), accV[i][1]);
        accV[i][2] = fdot2f(ai, f2h(wv0.z), accV[i][2]);
        accV[i][3] = fdot2f(ai, f2h(wv0.w), accV[i][3]);
        accV[i][4] = fdot2f(ai, f2h(wv1.x), accV[i][4]);
        accV[i][5] = fdot2f(ai, f2h(wv1.y), accV[i][5]);
        accV[i][6] = fdot2f(ai, f2h(wv1.z), accV[i][6]);
        accV[i][7] = fdot2f(ai, f2h(wv1.w), accV[i][7]);
      }
    }
  }
  // K: f16 row-major
  #pragma unroll
  for (int i = 0; i < 4; ++i) {
    size_t row = (size_t)(r0 + rowg*4 + i);
    float2 k0; k0.x = packh2(accK[i][0], accK[i][1]); k0.y = packh2(accK[i][2], accK[i][3]);
    float2 k1; k1.x = packh2(accK[i][4], accK[i][5]); k1.y = packh2(accK[i][6], accK[i][7]);
    *(float2*)&Khf[row*64 + (c0 >> 1)]      = k0;
    *(float2*)&Khf[row*64 + (c0 >> 1) + 32] = k1;
  }
  // V: f16 transposed [b][col][n] — thread's 4 rows are consecutive n
  int bb = r0 >> 11;
  int nn0 = (r0 & 2047) + rowg*4;
  #pragma unroll
  for (int j = 0; j < 8; ++j) {
    int col = (j < 4) ? (c0 + j) : (c0 + 60 + j);
    float2 vv; vv.x = packh2(accV[0][j], accV[1][j]); vv.y = packh2(accV[2][j], accV[3][j]);
    *(float2*)&VhTf[((size_t)bb*128 + col)*1024 + (nn0 >> 1)] = vv;
  }
}

// ---------------------------------------------------------------------------
// K4: Q = [last, load] @ Wq_last, fp32 compute, f16 output (R9 proven)
// ---------------------------------------------------------------------------
__global__ __launch_bounds__(256) void k_q(
    const float* __restrict__ last, const float* __restrict__ loadv,
    const float* __restrict__ Wq, float* __restrict__ Qhf)
{
  __shared__ __align__(16) float As[32*132];
  __shared__ __align__(16) float Ws[129*128];
  int tid = threadIdx.x;
  int r0 = blockIdx.x * 32;
  #pragma unroll
  for (int j = 0; j < 4; ++j) {
    int idx = tid + j*256;
    int row = idx >> 5, c4 = (idx & 31) << 2;
    *(float4*)&As[row*132 + c4] = *(const float4*)&last[(size_t)(r0 + row)*ED + c4];
  }
  if (tid < 32) As[tid*132 + 128] = loadv[r0 + tid];
  for (int idx = tid; idx < 4128; idx += 256)
    *(float4*)&Ws[idx*4] = *(const float4*)&Wq[idx*4];
  __syncthreads();

  int colg = tid & 15, rowg = tid >> 4;
  int c0 = colg << 2;
  float acc[2][8];
  #pragma unroll
  for (int i = 0; i < 2; ++i)
    #pragma unroll
    for (int j = 0; j < 8; ++j) acc[i][j] = 0.f;
  #pragma unroll 4
  for (int k = 0; k < 129; ++k) {
    float a0 = As[(rowg*2)*132 + k];
    float a1 = As[(rowg*2 + 1)*132 + k];
    float4 w0 = *(float4*)&Ws[k*128 + c0];
    float4 w1 = *(float4*)&Ws[k*128 + c0 + 64];
    acc[0][0] += a0*w0.x; acc[0][1] += a0*w0.y; acc[0][2] += a0*w0.z; acc[0][3] += a0*w0.w;
    acc[0][4] += a0*w1.x; acc[0][5] += a0*w1.y; acc[0][6] += a0*w1.z; acc[0][7] += a0*w1.w;
    acc[1][0] += a1*w0.x; acc[1][1] += a1*w0.y; acc[1][2] += a1*w0.z; acc[1][3] += a1*w0.w;
    acc[1][4] += a1*w1.x; acc[1][5] += a1*w1.y; acc[1][6] += a1*w1.z; acc[1][7] += a1*w1.w;
  }
  #pragma unroll
  for (int i = 0; i < 2; ++i) {
    size_t row = (size_t)(r0 + rowg*2 + i);
    float2 q0; q0.x = packh2(acc[i][0], acc[i][1]); q0.y = packh2(acc[i][2], acc[i][3]);
    float2 q1; q1.x = packh2(acc[i][4], acc[i][5]); q1.y = packh2(acc[i][6], acc[i][7]);
    *(float2*)&Qhf[row*64 + (c0 >> 1)]      = q0;
    *(float2*)&Qhf[row*64 + (c0 >> 1) + 32] = q1;
  }
}

// ---------------------------------------------------------------------------
// K5 v10: R10's proven f16 attention (2q/thread, 32q/block) + SPLIT-K:
// grid (128, 8, z=2); block z owns keys [1024z, 1024z+1024) = 8 tiles.
// Inner loop BYTE-IDENTICAL to R10 (88.5us proven). Staging+barriers+compute
// all halve together (R11's mistake: compute halved, staging didn't).
// 2048 blocks = 8/CU (VGPR 64 allows 32 waves/CU). Epilogue writes
// unnormalized partials {acc[16], m, l}; k_attn_merge combines.
// DO NOT add: reg prefetch, vectorized mask map, defer-max, bigger KVBLK
// (R2/R4/R5/R7 spilled). Guard: VGPR <= 64; WRITE ~5.4MB (partials, not GB).
// ---------------------------------------------------------------------------
__global__ __launch_bounds__(256, 4) void k_attn(
    const float* __restrict__ Khf, const float* __restrict__ VhTf,
    const float* __restrict__ Qhf, const float* __restrict__ mask,
    float* __restrict__ Part)
{
  __shared__ __align__(16) float kt[64*20];   // 64 key-pairs x (32 halfs + pad)
  __shared__ __align__(16) float vt[16*68];   // 16 d-rows x (128 key halfs + pad)
  int tid = threadIdx.x;
  int h = blockIdx.x & 7, b = blockIdx.x >> 3;
  int ph = blockIdx.y;
  int z  = blockIdx.z;
  int nq = tid & 15;
  int pg = tid >> 4;
  int prow0 = b*POMO + ph*32 + pg*2;
  const float* maskb = mask + (size_t)prow0 * PROBN;
  const float* Kb = Khf + (size_t)b*PROBN*64 + h*8;        // float units
  const float* Vb = VhTf + ((size_t)b*128 + h*16)*1024;    // d-row stride 1024 floats

  f16x2 q[2][8];
  #pragma unroll
  for (int qi = 0; qi < 2; ++qi) {
    const float* qp = Qhf + (size_t)(prow0 + qi)*64 + h*8;
    float4 t0 = *(const float4*)&qp[0];
    float4 t1 = *(const float4*)&qp[4];
    q[qi][0] = f2h(t0.x); q[qi][1] = f2h(t0.y); q[qi][2] = f2h(t0.z); q[qi][3] = f2h(t0.w);
    q[qi][4] = f2h(t1.x); q[qi][5] = f2h(t1.y); q[qi][6] = f2h(t1.z); q[qi][7] = f2h(t1.w);
  }
  float m[2], l[2], acc[2][16];
  #pragma unroll
  for (int qi = 0; qi < 2; ++qi) {
    m[qi] = -1.0e30f; l[qi] = 0.f;
    #pragma unroll
    for (int dd = 0; dd < 16; ++dd) acc[qi][dd] = 0.f;
  }

  int srow = tid >> 1, part = tid & 1;                  // K staging: 2 thr/row
  int kws = 20*(srow >> 1) + 8*(srow & 1) + 4*part;
  int vrow = tid >> 4, vchunk = tid & 15;               // V^T staging
  int vws = 68*vrow + 4*vchunk;

  for (int tile = 0; tile < 8; ++tile) {
    int t0 = (z << 10) + (tile << 7);                   // global key offset
    if (tile > 0) __syncthreads();
    *(float4*)&kt[kws] = *(const float4*)&Kb[(size_t)(t0 + srow)*64 + part*4];
    *(float4*)&vt[vws] = *(const float4*)&Vb[(size_t)vrow*1024 + (t0 >> 1) + vchunk*4];
    __syncthreads();

    // ---- scores (scalar mask loads, R6 style) ----
    float s[2][8];
    #pragma unroll
    for (int qi = 0; qi < 2; ++qi)
      #pragma unroll
      for (int i = 0; i < 4; ++i) {
        s[qi][2*i]   = maskb[(size_t)qi*PROBN + t0 + 2*nq + 32*i];
        s[qi][2*i+1] = maskb[(size_t)qi*PROBN + t0 + 2*nq + 32*i + 1];
      }
    #pragma unroll
    for (int i = 0; i < 4; ++i) {
      int p = nq + 16*i;
      float4 a0 = *(float4*)&kt[20*p];
      float4 a1 = *(float4*)&kt[20*p + 4];
      float4 b0 = *(float4*)&kt[20*p + 8];
      float4 b1 = *(float4*)&kt[20*p + 12];
      f16x2 ka[8] = {f2h(a0.x), f2h(a0.y), f2h(a0.z), f2h(a0.w),
                     f2h(a1.x), f2h(a1.y), f2h(a1.z), f2h(a1.w)};
      f16x2 kb[8] = {f2h(b0.x), f2h(b0.y), f2h(b0.z), f2h(b0.w),
                     f2h(b1.x), f2h(b1.y), f2h(b1.z), f2h(b1.w)};
      #pragma unroll
      for (int qi = 0; qi < 2; ++qi) {
        float d0 = 0.f, d1 = 0.f;
        #pragma unroll
        for (int j = 0; j < 8; ++j) {
          d0 = fdot2f(q[qi][j], ka[j], d0);
          d1 = fdot2f(q[qi][j], kb[j], d1);
        }
        s[qi][2*i]   += d0 * 0.25f;
        s[qi][2*i+1] += d1 * 0.25f;
      }
    }
    // ---- per-tile max merge + single unconditional rescale ----
    #pragma unroll
    for (int qi = 0; qi < 2; ++qi) {
      float tm = s[qi][0];
      #pragma unroll
      for (int i = 1; i < 8; ++i) tm = fmaxf(tm, s[qi][i]);
      float M = fmaxf(m[qi], tm);
      float c = __expf(m[qi] - M);
      m[qi] = M;
      l[qi] *= c;
      #pragma unroll
      for (int dd = 0; dd < 16; ++dd) acc[qi][dd] *= c;
    }
    // ---- exp + PV (pairwise fdot2 into fp32 acc) ----
    #pragma unroll
    for (int i = 0; i < 4; ++i) {
      int p = nq + 16*i;
      f16x2 wp0, wp1;
      {
        float w0 = __expf(s[0][2*i] - m[0]);
        float w1 = __expf(s[0][2*i+1] - m[0]);
        l[0] += w0 + w1;
        wp0.x = (f16)w0; wp0.y = (f16)w1;
        float u0 = __expf(s[1][2*i] - m[1]);
        float u1 = __expf(s[1][2*i+1] - m[1]);
        l[1] += u0 + u1;
        wp1.x = (f16)u0; wp1.y = (f16)u1;
      }
      #pragma unroll
      for (int dd = 0; dd < 16; ++dd) {
        f16x2 vh = f2h(vt[68*dd + p]);
        acc[0][dd] = fdot2f(wp0, vh, acc[0][dd]);
        acc[1][dd] = fdot2f(wp1, vh, acc[1][dd]);
      }
    }
  }

  // merge 16 stripes (tid bits 0..3, within wave)
  #pragma unroll
  for (int off = 1; off < 16; off <<= 1) {
    #pragma unroll
    for (int qi = 0; qi < 2; ++qi) {
      float m2 = __shfl_xor(m[qi], off);
      float l2 = __shfl_xor(l[qi], off);
      float M = fmaxf(m[qi], m2);
      float c1 = __expf(m[qi] - M), c2 = __expf(m2 - M);
      l[qi] = l[qi]*c1 + l2*c2;
      m[qi] = M;
      #pragma unroll
      for (int dd = 0; dd < 16; ++dd) {
        float a2 = __shfl_xor(acc[qi][dd], off);
        acc[qi][dd] = acc[qi][dd]*c1 + a2*c2;
      }
    }
  }
  // write unnormalized partial {acc[16], m, l} per (row, h, z); stride 20
  #pragma unroll
  for (int d4 = 0; d4 < 4; ++d4) {
    if (nq == d4) {
      #pragma unroll
      for (int qi = 0; qi < 2; ++qi) {
        float* pp = Part + (((size_t)(prow0 + qi)*8 + h)*2 + z)*20;
        *(float4*)&pp[4*d4] = make_float4(acc[qi][4*d4+0], acc[qi][4*d4+1],
                                          acc[qi][4*d4+2], acc[qi][4*d4+3]);
      }
    }
  }
  if (nq == 4) {
    #pragma unroll
    for (int qi = 0; qi < 2; ++qi) {
      float* pp = Part + (((size_t)(prow0 + qi)*8 + h)*2 + z)*20;
      pp[16] = m[qi];
      pp[17] = l[qi];
    }
  }
}

// ---------------------------------------------------------------------------
// K5b: merge the 2 split-K partials per (row,h) -> f16 Oph. 32768 threads.
// ---------------------------------------------------------------------------
__global__ __launch_bounds__(256) void k_attn_merge(
    const float* __restrict__ Part, float* __restrict__ Oph)
{
  int gid = blockIdx.x*256 + threadIdx.x;   // 0..32767 = r*8 + h
  int r = gid >> 3, h = gid & 7;
  const float* p0 = Part + (size_t)gid*40;
  const float* p1 = p0 + 20;
  float m0 = p0[16], l0 = p0[17];
  float m1 = p1[16], l1 = p1[17];
  float M  = fmaxf(m0, m1);
  float c0 = __expf(m0 - M), c1 = __expf(m1 - M);
  float rl = 1.f / (l0*c0 + l1*c1);
  float pk[8];
  #pragma unroll
  for (int j = 0; j < 4; ++j) {
    float4 a = *(const float4*)&p0[4*j];
    float4 bq = *(const float4*)&p1[4*j];
    float v0 = (a.x*c0 + bq.x*c1)*rl;
    float v1 = (a.y*c0 + bq.y*c1)*rl;
    float v2 = (a.z*c0 + bq.z*c1)*rl;
    float v3 = (a.w*c0 + bq.w*c1)*rl;
    pk[2*j]   = packh2(v0, v1);
    pk[2*j+1] = packh2(v2, v3);
  }
  float* op = &Oph[(size_t)r*64 + h*8];
  *(float4*)&op[0] = make_float4(pk[0], pk[1], pk[2], pk[3]);
  *(float4*)&op[4] = make_float4(pk[4], pk[5], pk[6], pk[7]);
}

// ---------------------------------------------------------------------------
// K6 v3: MH = Oph @ WCh[b] + BC[b], f16 fdot2, grid 256 (R10 proven).
// ---------------------------------------------------------------------------
__global__ __launch_bounds__(256) void k_mh(
    const float* __restrict__ Oph, const float* __restrict__ WCh,
    const float* __restrict__ BC, float* __restrict__ MH)
{
  __shared__ __align__(16) float Ash[16*66];    // 16 rows x 64 d-pairs (+pad)
  __shared__ __align__(16) float Wp[64*128];    // 32KB f16 pairs [p][c]
  int tid = threadIdx.x;
  int b = blockIdx.x >> 4;
  int pt = blockIdx.x & 15;
  int r0 = b*POMO + pt*16;
  {
    int row = tid >> 4, c4 = (tid & 15) << 2;
    *(float4*)&Ash[row*66 + c4] = *(const float4*)&Oph[(size_t)(r0 + row)*64 + c4];
  }
  #pragma unroll
  for (int j = 0; j < 8; ++j) {
    int wi = tid + j*256;
    *(float4*)&Wp[wi*4] = *(const float4*)&WCh[(size_t)b*8192 + wi*4];
  }
  __syncthreads();

  int colg = tid & 15, rowg = tid >> 4;
  int c0 = colg << 2;
  float4 b0 = *(const float4*)&BC[b*ED + c0];
  float4 b1 = *(const float4*)&BC[b*ED + c0 + 64];
  float acc[8] = {b0.x, b0.y, b0.z, b0.w, b1.x, b1.y, b1.z, b1.w};
  #pragma unroll 4
  for (int p = 0; p < 64; ++p) {
    f16x2 a = f2h(Ash[rowg*66 + p]);
    float4 w0 = *(float4*)&Wp[p*128 + c0];
    float4 w1 = *(float4*)&Wp[p*128 + c0 + 64];
    acc[0] = fdot2f(a, f2h(w0.x), acc[0]);
    acc[1] = fdot2f(a, f2h(w0.y), acc[1]);
    acc[2] = fdot2f(a, f2h(w0.z), acc[2]);
    acc[3] = fdot2f(a, f2h(w0.w), acc[3]);
    acc[4] = fdot2f(a, f2h(w1.x), acc[4]);
    acc[5] = fdot2f(a, f2h(w1.y), acc[5]);
    acc[6] = fdot2f(a, f2h(w1.z), acc[6]);
    acc[7] = fdot2f(a, f2h(w1.w), acc[7]);
  }
  size_t row = (size_t)(r0 + rowg) * ED;
  *(float4*)&MH[row + c0]      = make_float4(acc[0], acc[1], acc[2], acc[3]);
  *(float4*)&MH[row + c0 + 64] = make_float4(acc[4], acc[5], acc[6], acc[7]);
}

// ---------------------------------------------------------------------------
// K7 v3 (R10 proven): score2 = MH @ nodes^T / sqrt(E) via f16 fdot2;
// probs = softmax. Phase 2 wave-parallel, 8 p-rows/block, grid 512.
// (R11's 4-row split doubled Nhf streaming — reverted.)
// ---------------------------------------------------------------------------
__global__ __launch_bounds__(256) void k_final(
    const float* __restrict__ MH, const float* __restrict__ Nhf,
    const float* __restrict__ mask, float* __restrict__ probs)
{
  __shared__ __align__(16) float lg[8*PROBN];     // 64 KB
  __shared__ __align__(16) float mh8[8*68];       // f16 MH rows
  int tid = threadIdx.x;
  int b = blockIdx.x >> 5;
  int p0 = (blockIdx.x & 31) * 8;
  {
    int row = tid >> 5, c4 = (tid & 31) << 2;
    float4 v = *(const float4*)&MH[(size_t)(b*POMO + p0 + row)*ED + c4];
    float2 hh; hh.x = packh2(v.x, v.y); hh.y = packh2(v.z, v.w);
    *(float2*)&mh8[row*68 + (c4 >> 1)] = hh;
  }
  __syncthreads();
  const float invs = 0.08838834764831845f;        // 1/sqrt(128)
  #pragma unroll
  for (int j = 0; j < 8; ++j) {
    int n = tid + (j << 8);
    const float* nr = &Nhf[(size_t)(b*PROBN + n)*64];
    float a[8];
    #pragma unroll
    for (int p = 0; p < 8; ++p) a[p] = 0.f;
    #pragma unroll 4
    for (int kq = 0; kq < 16; ++kq) {
      float4 nv = *(const float4*)&nr[kq*4];
      f16x2 n0 = f2h(nv.x), n1 = f2h(nv.y), n2 = f2h(nv.z), n3 = f2h(nv.w);
      #pragma unroll
      for (int p = 0; p < 8; ++p) {
        float4 mv = *(const float4*)&mh8[p*68 + kq*4];
        a[p] = fdot2f(f2h(mv.x), n0, a[p]);
        a[p] = fdot2f(f2h(mv.y), n1, a[p]);
        a[p] = fdot2f(f2h(mv.z), n2, a[p]);
        a[p] = fdot2f(f2h(mv.w), n3, a[p]);
      }
    }
    #pragma unroll
    for (int p = 0; p < 8; ++p) lg[p*PROBN + n] = a[p] * invs;
  }
  __syncthreads();

  int wid = tid >> 6, lane = tid & 63;
  #pragma unroll
  for (int pp = 0; pp < 2; ++pp) {
    int p = wid*2 + pp;
    const float* mrow = mask + (size_t)(b*POMO + p0 + p) * PROBN;
    float* prow = probs + (size_t)(b*POMO + p0 + p) * PROBN;
    float z[32];
    float mx = -3.0e38f;
    #pragma unroll
    for (int i4 = 0; i4 < 8; ++i4) {
      int n = 4*lane + 256*i4;
      float4 lv = *(const float4*)&lg[p*PROBN + n];
      float4 mv = *(const float4*)&mrow[n];
      float z0 = 10.f - 20.f/(__expf(2.f*lv.x)+1.f) + mv.x;
      float z1 = 10.f - 20.f/(__expf(2.f*lv.y)+1.f) + mv.y;
      float z2 = 10.f - 20.f/(__expf(2.f*lv.z)+1.f) + mv.z;
      float z3 = 10.f - 20.f/(__expf(2.f*lv.w)+1.f) + mv.w;
      z[4*i4+0] = z0; z[4*i4+1] = z1; z[4*i4+2] = z2; z[4*i4+3] = z3;
      mx = fmaxf(fmaxf(fmaxf(mx, z0), fmaxf(z1, z2)), z3);
    }
    #pragma unroll
    for (int off = 32; off > 0; off >>= 1) mx = fmaxf(mx, __shfl_xor(mx, off));
    float sum = 0.f;
    #pragma unroll
    for (int k = 0; k < 32; ++k) { z[k] = __expf(z[k] - mx); sum += z[k]; }
    #pragma unroll
    for (int off = 32; off > 0; off >>= 1) sum += __shfl_xor(sum, off);
    float rs = 1.f / sum;
    #pragma unroll
    for (int i4 = 0; i4 < 8; ++i4) {
      int n = 4*lane + 256*i4;
      *(float4*)&prow[n] = make_float4(z[4*i4+0]*rs, z[4*i4+1]*rs,
                                       z[4*i4+2]*rs, z[4*i4+3]*rs);
    }
  }
}

// ---------------------------------------------------------------------------
extern "C" void kernel_launch(void* const* d_in, const int* in_sizes, int n_in,
                              void* d_out, int out_size, void* d_ws, size_t ws_size,
                              hipStream_t stream)
{
  const float* nodes  = (const float*)d_in[0];
  const float* last   = (const float*)d_in[1];
  const float* mid    = (const float*)d_in[2];
  const float* loadv  = (const float*)d_in[3];
  const float* mask   = (const float*)d_in[4];
  const float* Wq     = (const float*)d_in[5];
  const float* Wk     = (const float*)d_in[6];
  const float* Wv     = (const float*)d_in[7];
  const float* eW     = (const float*)d_in[8];
  const float* eB     = (const float*)d_in[9];
  const float* w_gate = (const float*)d_in[10];
  float* out = (float*)d_out;
  float* ws  = (float*)d_ws;

  k_gating<<<1, 128, 0, stream>>>(mid, w_gate, ws + WS_GATES, out + BB*POMO*PROBN);
  k_experts<<<128, 256, 0, stream>>>(ws + WS_GATES, eW, eB, ws + WS_WC, ws + WS_BC);
  k_kv<<<512, 256, 0, stream>>>(nodes, Wk, Wv, ws + WS_KH, ws + WS_VHT, ws + WS_NH);
  k_q<<<128, 256, 0, stream>>>(last, loadv, Wq, ws + WS_QH);
  k_attn<<<dim3(128, 8, 2), 256, 0, stream>>>(ws + WS_KH, ws + WS_VHT, ws + WS_QH, mask, ws + WS_PART);
  k_attn_merge<<<128, 256, 0, stream>>>(ws + WS_PART, ws + WS_OUT);
  k_mh<<<256, 256, 0, stream>>>(ws + WS_OUT, ws + WS_WC, ws + WS_BC, ws + WS_MH);
  k_final<<<512, 256, 0, stream>>>(ws + WS_MH, ws + WS_NH, mask, out);
}

// Round 13
// 167.045 us; speedup vs baseline: 1.3409x; 1.1241x over previous
//
#include <hip/hip_runtime.h>
#include <math.h>

#define BB    16
#define PROBN 2048
#define POMO  256
#define ED    128
#define HN    8
#define DDIM  16
#define NEXP  8

typedef _Float16 f16;
typedef f16 f16x2 __attribute__((ext_vector_type(2)));

__device__ __forceinline__ f16x2 f2h(float f) {
  union U { float f; f16x2 h; } u; u.f = f; return u.h;
}
__device__ __forceinline__ float packh2(float a, float b) {
  union U { float f; f16x2 h; } u; u.h.x = (f16)a; u.h.y = (f16)b; return u.f;
}
__device__ __forceinline__ float fdot2f(f16x2 a, f16x2 b, float c) {
#if __has_builtin(__builtin_amdgcn_fdot2)
  return __builtin_amdgcn_fdot2(a, b, c, false);
#else
  return c + (float)a.x * (float)b.x + (float)a.y * (float)b.y;
#endif
}

// ws float offsets (f16 arrays addressed as float*)
#define WS_KH    0                        // f16 K [b][n][h*16+d]    (2,097,152 floats)
#define WS_VHT   (WS_KH + 2097152)        // f16 V^T [b][h*16+d][n]  (2,097,152)
#define WS_NH    (WS_VHT + 2097152)       // f16 nodes [b][n][d]     (2,097,152)
#define WS_QH    (WS_NH + 2097152)        // f16 Q [b*POMO][d]       (262,144)
#define WS_OUT   (WS_QH + 262144)         // f16 attn out [row][64f] (262,144)
#define WS_MH    (WS_OUT + 262144)        // fp32 MoE out            (524,288)
#define WS_WC    (WS_MH + 524288)         // f16 WC pairs [b][p][c]  (131,072)
#define WS_BC    (WS_WC + 131072)         // fp32 combined bias      (2,048)
#define WS_GATES (WS_BC + 2048)           // fp32 gates              (128)

// ---------------------------------------------------------------------------
// K1: gating (top-2 softmax), gates -> ws, moe_loss -> d_out tail. FP32-EXACT.
// ---------------------------------------------------------------------------
__global__ __launch_bounds__(128) void k_gating(
    const float* __restrict__ mid, const float* __restrict__ w_gate,
    float* __restrict__ gates_ws, float* __restrict__ moe_out)
{
  __shared__ float lg[BB][NEXP];
  __shared__ float gt[BB][NEXP];
  int t = threadIdx.x;
  {
    int b = t >> 3, e = t & 7;
    float acc = 0.f;
    #pragma unroll 8
    for (int k = 0; k < ED; ++k) acc += mid[b*ED + k] * w_gate[k*NEXP + e];
    lg[b][e] = acc;
  }
  __syncthreads();
  if (t < BB) {
    int b = t;
    int i1 = 0; float v1 = lg[b][0];
    #pragma unroll
    for (int e = 1; e < NEXP; ++e) if (lg[b][e] > v1) { v1 = lg[b][e]; i1 = e; }
    int i2 = -1; float v2 = -3.0e38f;
    #pragma unroll
    for (int e = 0; e < NEXP; ++e) if (e != i1 && lg[b][e] > v2) { v2 = lg[b][e]; i2 = e; }
    float e2 = __expf(v2 - v1);          // <= 1
    float g1 = 1.f / (1.f + e2);
    #pragma unroll
    for (int e = 0; e < NEXP; ++e) gt[b][e] = 0.f;
    gt[b][i1] = g1;
    gt[b][i2] = e2 * g1;
  }
  __syncthreads();
  if (t < BB*NEXP) gates_ws[t] = gt[t >> 3][t & 7];
  if (t == 0) {
    float imp[NEXP], ldc[NEXP];
    #pragma unroll
    for (int e = 0; e < NEXP; ++e) { imp[e] = 0.f; ldc[e] = 0.f; }
    for (int b = 0; b < BB; ++b)
      #pragma unroll
      for (int e = 0; e < NEXP; ++e) {
        float g = gt[b][e];
        imp[e] += g;
        if (g > 0.f) ldc[e] += 1.f;
      }
    float im = 0.f, lm = 0.f;
    #pragma unroll
    for (int e = 0; e < NEXP; ++e) { im += imp[e]; lm += ldc[e]; }
    im *= 0.125f; lm *= 0.125f;
    float iv = 0.f, lv = 0.f;
    #pragma unroll
    for (int e = 0; e < NEXP; ++e) {
      float a = imp[e] - im; iv += a*a;
      float c = ldc[e] - lm; lv += c*c;
    }
    iv *= 0.125f; lv *= 0.125f;
    moe_out[0] = iv / (im*im + 1e-10f) + lv / (lm*lm + 1e-10f);
  }
}

// ---------------------------------------------------------------------------
// K2 v3: WCh[b] = f16 (k,k+1)-pairs of sum_e g_e*expert_W[e]; BC fp32.
// ---------------------------------------------------------------------------
__global__ __launch_bounds__(256) void k_experts(
    const float* __restrict__ gates, const float* __restrict__ eW,
    const float* __restrict__ eB, float* __restrict__ WCh, float* __restrict__ BC)
{
  __shared__ float g[NEXP];
  int tid = threadIdx.x;
  int b = blockIdx.x >> 3;
  int tile = blockIdx.x & 7;           // 8 tiles of 1024 packed floats
  if (tid < NEXP) g[tid] = gates[b*NEXP + tid];
  __syncthreads();
  int i0 = tile * 1024;
  #pragma unroll
  for (int j = 0; j < 4; ++j) {
    int pi = i0 + tid + j*256;         // packed index: p*128 + c
    int k2 = (pi >> 7) << 1;           // 2p
    int c  = pi & 127;
    float a0 = 0.f, a1 = 0.f;
    #pragma unroll
    for (int e = 0; e < NEXP; ++e) {
      a0 += g[e] * eW[e*ED*ED + k2*ED + c];
      a1 += g[e] * eW[e*ED*ED + (k2+1)*ED + c];
    }
    WCh[(size_t)b*8192 + pi] = packh2(a0, a1);
  }
  if (tile == 0 && tid < ED) {
    float a = 0.f;
    #pragma unroll
    for (int e = 0; e < NEXP; ++e) a += g[e] * eB[e*ED + tid];
    BC[b*ED + tid] = a;
  }
}

// ---------------------------------------------------------------------------
// K3 v4: K/V projection with f16 fdot2 inner loop (R10 proven).
// ---------------------------------------------------------------------------
__global__ __launch_bounds__(256) void k_kv(
    const float* __restrict__ nodes, const float* __restrict__ Wk,
    const float* __restrict__ Wv, float* __restrict__ Khf,
    float* __restrict__ VhTf, float* __restrict__ Nhf)
{
  __shared__ __align__(16) float Ash[64*66];     // 64 rows x (64 d-pairs + 2 pad)
  __shared__ __align__(16) float Wkp[16*128];    // f16 pairs [p][c]
  __shared__ __align__(16) float Wvp[16*128];
  int tid = threadIdx.x;
  int r0 = blockIdx.x * 64;
  #pragma unroll
  for (int j = 0; j < 8; ++j) {
    int idx = tid + j*256;
    int row = idx >> 5, c4 = (idx & 31) << 2;
    float4 v = *(const float4*)&nodes[(size_t)(r0 + row)*ED + c4];
    float2 nh; nh.x = packh2(v.x, v.y); nh.y = packh2(v.z, v.w);
    *(float2*)&Ash[row*66 + (c4 >> 1)] = nh;
    *(float2*)&Nhf[(size_t)(r0 + row)*64 + (c4 >> 1)] = nh;
  }
  int colg = tid & 15, rowg = tid >> 4;
  int c0 = colg << 2;              // cols c0..c0+3 and c0+64..c0+67
  float accK[4][8], accV[4][8];
  #pragma unroll
  for (int i = 0; i < 4; ++i)
    #pragma unroll
    for (int j = 0; j < 8; ++j) { accK[i][j] = 0.f; accV[i][j] = 0.f; }

  for (int kk = 0; kk < 128; kk += 32) {
    __syncthreads();
    #pragma unroll
    for (int j = 0; j < 2; ++j) {
      int wi = tid + j*256;
      int p = wi >> 5, c4 = (wi & 31) << 2;
      float4 ka = *(const float4*)&Wk[(kk + 2*p)*ED + c4];
      float4 kb = *(const float4*)&Wk[(kk + 2*p + 1)*ED + c4];
      float4 pk; pk.x = packh2(ka.x, kb.x); pk.y = packh2(ka.y, kb.y);
      pk.z = packh2(ka.z, kb.z); pk.w = packh2(ka.w, kb.w);
      *(float4*)&Wkp[p*128 + c4] = pk;
      float4 va = *(const float4*)&Wv[(kk + 2*p)*ED + c4];
      float4 vb = *(const float4*)&Wv[(kk + 2*p + 1)*ED + c4];
      float4 pv; pv.x = packh2(va.x, vb.x); pv.y = packh2(va.y, vb.y);
      pv.z = packh2(va.z, vb.z); pv.w = packh2(va.w, vb.w);
      *(float4*)&Wvp[p*128 + c4] = pv;
    }
    __syncthreads();
    #pragma unroll 4
    for (int p = 0; p < 16; ++p) {
      float ap[4];
      #pragma unroll
      for (int i = 0; i < 4; ++i) ap[i] = Ash[(rowg*4 + i)*66 + (kk >> 1) + p];
      float4 wk0 = *(float4*)&Wkp[p*128 + c0];
      float4 wk1 = *(float4*)&Wkp[p*128 + c0 + 64];
      float4 wv0 = *(float4*)&Wvp[p*128 + c0];
      float4 wv1 = *(float4*)&Wvp[p*128 + c0 + 64];
      #pragma unroll
      for (int i = 0; i < 4; ++i) {
        f16x2 ai = f2h(ap[i]);
        accK[i][0] = fdot2f(ai, f2h(wk0.x), accK[i][0]);
        accK[i][1] = fdot2f(ai, f2h(wk0.y), accK[i][1]);
        accK[i][2] = fdot2f(ai, f2h(wk0.z), accK[i][2]);
        accK[i][3] = fdot2f(ai, f2h(wk0.w), accK[i][3]);
        accK[i][4] = fdot2f(ai, f2h(wk1.x), accK[i][4]);
        accK[i][5] = fdot2f(ai, f2h(wk1.y), accK[i][5]);
        accK[i][6] = fdot2f(ai, f2h(wk1.z), accK[i][6]);
        accK[i][7] = fdot2f(ai, f2h(wk1.w), accK[i][7]);
        accV[i][0] = fdot2f(ai, f2h(wv0.x), accV[i][0]);
        accV[i][1] = fdot2f(ai, f2h(wv0.y), accV[i][1]);
        accV[i][2] = fdot2f(ai, f2h(wv0.z), accV[i][2]);
        accV[i][3] = fdot2f(ai, f2h(wv0.w), accV[i][3]);
        accV[i][4] = fdot2f(ai, f2h(wv1.x), accV[i][4]);
        accV[i][5] = fdot2f(ai, f2h(wv1.y), accV[i][5]);
        accV[i][6] = fdot2f(ai, f2h(wv1.z), accV[i][6]);
        accV[i][7] = fdot2f(ai, f2h(wv1.w), accV[i][7]);
      }
    }
  }
  // K: f16 row-major
  #pragma unroll
  for (int i = 0; i < 4; ++i) {
    size_t row = (size_t)(r0 + rowg*4 + i);
    float2 k0; k0.x = packh2(accK[i][0], accK[i][1]); k0.y = packh2(accK[i][2], accK[i][3]);
    float2 k1; k1.x = packh2(accK[i][4], accK[i][5]); k1.y = packh2(accK[i][6], accK[i][7]);
    *(float2*)&Khf[row*64 + (c0 >> 1)]      = k0;
    *(float2*)&Khf[row*64 + (c0 >> 1) + 32] = k1;
  }
  // V: f16 transposed [b][col][n] — thread's 4 rows are consecutive n
  int bb = r0 >> 11;
  int nn0 = (r0 & 2047) + rowg*4;
  #pragma unroll
  for (int j = 0; j < 8; ++j) {
    int col = (j < 4) ? (c0 + j) : (c0 + 60 + j);
    float2 vv; vv.x = packh2(accV[0][j], accV[1][j]); vv.y = packh2(accV[2][j], accV[3][j]);
    *(float2*)&VhTf[((size_t)bb*128 + col)*1024 + (nn0 >> 1)] = vv;
  }
}

// ---------------------------------------------------------------------------
// K4: Q = [last, load] @ Wq_last, fp32 compute, f16 output (R9 proven)
// ---------------------------------------------------------------------------
__global__ __launch_bounds__(256) void k_q(
    const float* __restrict__ last, const float* __restrict__ loadv,
    const float* __restrict__ Wq, float* __restrict__ Qhf)
{
  __shared__ __align__(16) float As[32*132];
  __shared__ __align__(16) float Ws[129*128];
  int tid = threadIdx.x;
  int r0 = blockIdx.x * 32;
  #pragma unroll
  for (int j = 0; j < 4; ++j) {
    int idx = tid + j*256;
    int row = idx >> 5, c4 = (idx & 31) << 2;
    *(float4*)&As[row*132 + c4] = *(const float4*)&last[(size_t)(r0 + row)*ED + c4];
  }
  if (tid < 32) As[tid*132 + 128] = loadv[r0 + tid];
  for (int idx = tid; idx < 4128; idx += 256)
    *(float4*)&Ws[idx*4] = *(const float4*)&Wq[idx*4];
  __syncthreads();

  int colg = tid & 15, rowg = tid >> 4;
  int c0 = colg << 2;
  float acc[2][8];
  #pragma unroll
  for (int i = 0; i < 2; ++i)
    #pragma unroll
    for (int j = 0; j < 8; ++j) acc[i][j] = 0.f;
  #pragma unroll 4
  for (int k = 0; k < 129; ++k) {
    float a0 = As[(rowg*2)*132 + k];
    float a1 = As[(rowg*2 + 1)*132 + k];
    float4 w0 = *(float4*)&Ws[k*128 + c0];
    float4 w1 = *(float4*)&Ws[k*128 + c0 + 64];
    acc[0][0] += a0*w0.x; acc[0][1] += a0*w0.y; acc[0][2] += a0*w0.z; acc[0][3] += a0*w0.w;
    acc[0][4] += a0*w1.x; acc[0][5] += a0*w1.y; acc[0][6] += a0*w1.z; acc[0][7] += a0*w1.w;
    acc[1][0] += a1*w0.x; acc[1][1] += a1*w0.y; acc[1][2] += a1*w0.z; acc[1][3] += a1*w0.w;
    acc[1][4] += a1*w1.x; acc[1][5] += a1*w1.y; acc[1][6] += a1*w1.z; acc[1][7] += a1*w1.w;
  }
  #pragma unroll
  for (int i = 0; i < 2; ++i) {
    size_t row = (size_t)(r0 + rowg*2 + i);
    float2 q0; q0.x = packh2(acc[i][0], acc[i][1]); q0.y = packh2(acc[i][2], acc[i][3]);
    float2 q1; q1.x = packh2(acc[i][4], acc[i][5]); q1.y = packh2(acc[i][6], acc[i][7]);
    *(float2*)&Qhf[row*64 + (c0 >> 1)]      = q0;
    *(float2*)&Qhf[row*64 + (c0 >> 1) + 32] = q1;
  }
}

// ---------------------------------------------------------------------------
// K5 v11 = R10's proven f16 attention body (88.5us), XCD-aware 1D grid:
// id = h*128 + ph*16 + b  ->  id%8 = b%8, so blocks sharing the same mask
// slice (same b,ph; h varies, delta=128) AND blocks sharing K/V (same b,h;
// ph varies, delta=16) land on the SAME XCD -> L2 absorbs the 8x mask and
// 8x K/V re-reads (FETCH was 195MB vs ideal 52MB with the old mapping).
// Main loop FROZEN. DO NOT add: reg prefetch, vectorized mask map,
// defer-max, bigger KVBLK, split-K (R2/R4/R5/R7 spilled; R11/R12 null).
// Guard: VGPR <= 64; WRITE_SIZE KB-scale.
// ---------------------------------------------------------------------------
__global__ __launch_bounds__(256, 4) void k_attn(
    const float* __restrict__ Khf, const float* __restrict__ VhTf,
    const float* __restrict__ Qhf, const float* __restrict__ mask,
    float* __restrict__ Oph)
{
  __shared__ __align__(16) float kt[64*20];   // 64 key-pairs x (32 halfs + pad)
  __shared__ __align__(16) float vt[16*68];   // 16 d-rows x (128 key halfs + pad)
  int tid = threadIdx.x;
  int id = blockIdx.x;
  int h  = id >> 7;
  int ph = (id >> 4) & 7;
  int b  = id & 15;
  int nq = tid & 15;
  int pg = tid >> 4;
  int prow0 = b*POMO + ph*32 + pg*2;
  const float* maskb = mask + (size_t)prow0 * PROBN;
  const float* Kb = Khf + (size_t)b*PROBN*64 + h*8;        // float units
  const float* Vb = VhTf + ((size_t)b*128 + h*16)*1024;    // d-row stride 1024 floats

  f16x2 q[2][8];
  #pragma unroll
  for (int qi = 0; qi < 2; ++qi) {
    const float* qp = Qhf + (size_t)(prow0 + qi)*64 + h*8;
    float4 t0 = *(const float4*)&qp[0];
    float4 t1 = *(const float4*)&qp[4];
    q[qi][0] = f2h(t0.x); q[qi][1] = f2h(t0.y); q[qi][2] = f2h(t0.z); q[qi][3] = f2h(t0.w);
    q[qi][4] = f2h(t1.x); q[qi][5] = f2h(t1.y); q[qi][6] = f2h(t1.z); q[qi][7] = f2h(t1.w);
  }
  float m[2], l[2], acc[2][16];
  #pragma unroll
  for (int qi = 0; qi < 2; ++qi) {
    m[qi] = -1.0e30f; l[qi] = 0.f;
    #pragma unroll
    for (int dd = 0; dd < 16; ++dd) acc[qi][dd] = 0.f;
  }

  int srow = tid >> 1, part = tid & 1;                  // K staging: 2 thr/row
  int kws = 20*(srow >> 1) + 8*(srow & 1) + 4*part;
  int vrow = tid >> 4, vchunk = tid & 15;               // V^T staging
  int vws = 68*vrow + 4*vchunk;

  for (int tile = 0; tile < 16; ++tile) {
    int t0 = tile << 7;
    if (tile > 0) __syncthreads();
    *(float4*)&kt[kws] = *(const float4*)&Kb[(size_t)(t0 + srow)*64 + part*4];
    *(float4*)&vt[vws] = *(const float4*)&Vb[(size_t)vrow*1024 + (t0 >> 1) + vchunk*4];
    __syncthreads();

    // ---- scores (scalar mask loads, R6 style) ----
    float s[2][8];
    #pragma unroll
    for (int qi = 0; qi < 2; ++qi)
      #pragma unroll
      for (int i = 0; i < 4; ++i) {
        s[qi][2*i]   = maskb[(size_t)qi*PROBN + t0 + 2*nq + 32*i];
        s[qi][2*i+1] = maskb[(size_t)qi*PROBN + t0 + 2*nq + 32*i + 1];
      }
    #pragma unroll
    for (int i = 0; i < 4; ++i) {
      int p = nq + 16*i;
      float4 a0 = *(float4*)&kt[20*p];
      float4 a1 = *(float4*)&kt[20*p + 4];
      float4 b0 = *(float4*)&kt[20*p + 8];
      float4 b1 = *(float4*)&kt[20*p + 12];
      f16x2 ka[8] = {f2h(a0.x), f2h(a0.y), f2h(a0.z), f2h(a0.w),
                     f2h(a1.x), f2h(a1.y), f2h(a1.z), f2h(a1.w)};
      f16x2 kb[8] = {f2h(b0.x), f2h(b0.y), f2h(b0.z), f2h(b0.w),
                     f2h(b1.x), f2h(b1.y), f2h(b1.z), f2h(b1.w)};
      #pragma unroll
      for (int qi = 0; qi < 2; ++qi) {
        float d0 = 0.f, d1 = 0.f;
        #pragma unroll
        for (int j = 0; j < 8; ++j) {
          d0 = fdot2f(q[qi][j], ka[j], d0);
          d1 = fdot2f(q[qi][j], kb[j], d1);
        }
        s[qi][2*i]   += d0 * 0.25f;
        s[qi][2*i+1] += d1 * 0.25f;
      }
    }
    // ---- per-tile max merge + single unconditional rescale ----
    #pragma unroll
    for (int qi = 0; qi < 2; ++qi) {
      float tm = s[qi][0];
      #pragma unroll
      for (int i = 1; i < 8; ++i) tm = fmaxf(tm, s[qi][i]);
      float M = fmaxf(m[qi], tm);
      float c = __expf(m[qi] - M);
      m[qi] = M;
      l[qi] *= c;
      #pragma unroll
      for (int dd = 0; dd < 16; ++dd) acc[qi][dd] *= c;
    }
    // ---- exp + PV (pairwise fdot2 into fp32 acc) ----
    #pragma unroll
    for (int i = 0; i < 4; ++i) {
      int p = nq + 16*i;
      f16x2 wp0, wp1;
      {
        float w0 = __expf(s[0][2*i] - m[0]);
        float w1 = __expf(s[0][2*i+1] - m[0]);
        l[0] += w0 + w1;
        wp0.x = (f16)w0; wp0.y = (f16)w1;
        float u0 = __expf(s[1][2*i] - m[1]);
        float u1 = __expf(s[1][2*i+1] - m[1]);
        l[1] += u0 + u1;
        wp1.x = (f16)u0; wp1.y = (f16)u1;
      }
      #pragma unroll
      for (int dd = 0; dd < 16; ++dd) {
        f16x2 vh = f2h(vt[68*dd + p]);
        acc[0][dd] = fdot2f(wp0, vh, acc[0][dd]);
        acc[1][dd] = fdot2f(wp1, vh, acc[1][dd]);
      }
    }
  }

  // merge 16 stripes (tid bits 0..3, within wave)
  #pragma unroll
  for (int off = 1; off < 16; off <<= 1) {
    #pragma unroll
    for (int qi = 0; qi < 2; ++qi) {
      float m2 = __shfl_xor(m[qi], off);
      float l2 = __shfl_xor(l[qi], off);
      float M = fmaxf(m[qi], m2);
      float c1 = __expf(m[qi] - M), c2 = __expf(m2 - M);
      l[qi] = l[qi]*c1 + l2*c2;
      m[qi] = M;
      #pragma unroll
      for (int dd = 0; dd < 16; ++dd) {
        float a2 = __shfl_xor(acc[qi][dd], off);
        acc[qi][dd] = acc[qi][dd]*c1 + a2*c2;
      }
    }
  }
  // write f16-packed: lanes nq<4, compile-time indexed (rule #20)
  #pragma unroll
  for (int d4 = 0; d4 < 4; ++d4) {
    if (nq == d4) {
      #pragma unroll
      for (int qi = 0; qi < 2; ++qi) {
        float rl = 1.f / l[qi];
        float2 o;
        o.x = packh2(acc[qi][4*d4+0]*rl, acc[qi][4*d4+1]*rl);
        o.y = packh2(acc[qi][4*d4+2]*rl, acc[qi][4*d4+3]*rl);
        *(float2*)&Oph[(size_t)(prow0 + qi)*64 + h*8 + d4*2] = o;
      }
    }
  }
}

// ---------------------------------------------------------------------------
// K6 v3: MH = Oph @ WCh[b] + BC[b], f16 fdot2, grid 256 (R10 proven).
// ---------------------------------------------------------------------------
__global__ __launch_bounds__(256) void k_mh(
    const float* __restrict__ Oph, const float* __restrict__ WCh,
    const float* __restrict__ BC, float* __restrict__ MH)
{
  __shared__ __align__(16) float Ash[16*66];    // 16 rows x 64 d-pairs (+pad)
  __shared__ __align__(16) float Wp[64*128];    // 32KB f16 pairs [p][c]
  int tid = threadIdx.x;
  int b = blockIdx.x >> 4;
  int pt = blockIdx.x & 15;
  int r0 = b*POMO + pt*16;
  {
    int row = tid >> 4, c4 = (tid & 15) << 2;
    *(float4*)&Ash[row*66 + c4] = *(const float4*)&Oph[(size_t)(r0 + row)*64 + c4];
  }
  #pragma unroll
  for (int j = 0; j < 8; ++j) {
    int wi = tid + j*256;
    *(float4*)&Wp[wi*4] = *(const float4*)&WCh[(size_t)b*8192 + wi*4];
  }
  __syncthreads();

  int colg = tid & 15, rowg = tid >> 4;
  int c0 = colg << 2;
  float4 b0 = *(const float4*)&BC[b*ED + c0];
  float4 b1 = *(const float4*)&BC[b*ED + c0 + 64];
  float acc[8] = {b0.x, b0.y, b0.z, b0.w, b1.x, b1.y, b1.z, b1.w};
  #pragma unroll 4
  for (int p = 0; p < 64; ++p) {
    f16x2 a = f2h(Ash[rowg*66 + p]);
    float4 w0 = *(float4*)&Wp[p*128 + c0];
    float4 w1 = *(float4*)&Wp[p*128 + c0 + 64];
    acc[0] = fdot2f(a, f2h(w0.x), acc[0]);
    acc[1] = fdot2f(a, f2h(w0.y), acc[1]);
    acc[2] = fdot2f(a, f2h(w0.z), acc[2]);
    acc[3] = fdot2f(a, f2h(w0.w), acc[3]);
    acc[4] = fdot2f(a, f2h(w1.x), acc[4]);
    acc[5] = fdot2f(a, f2h(w1.y), acc[5]);
    acc[6] = fdot2f(a, f2h(w1.z), acc[6]);
    acc[7] = fdot2f(a, f2h(w1.w), acc[7]);
  }
  size_t row = (size_t)(r0 + rowg) * ED;
  *(float4*)&MH[row + c0]      = make_float4(acc[0], acc[1], acc[2], acc[3]);
  *(float4*)&MH[row + c0 + 64] = make_float4(acc[4], acc[5], acc[6], acc[7]);
}

// ---------------------------------------------------------------------------
// K7 v3 (R10 proven): score2 = MH @ nodes^T / sqrt(E) via f16 fdot2;
// probs = softmax. Phase 2 wave-parallel, 8 p-rows/block, grid 512.
// ---------------------------------------------------------------------------
__global__ __launch_bounds__(256) void k_final(
    const float* __restrict__ MH, const float* __restrict__ Nhf,
    const float* __restrict__ mask, float* __restrict__ probs)
{
  __shared__ __align__(16) float lg[8*PROBN];     // 64 KB
  __shared__ __align__(16) float mh8[8*68];       // f16 MH rows
  int tid = threadIdx.x;
  int b = blockIdx.x >> 5;
  int p0 = (blockIdx.x & 31) * 8;
  {
    int row = tid >> 5, c4 = (tid & 31) << 2;
    float4 v = *(const float4*)&MH[(size_t)(b*POMO + p0 + row)*ED + c4];
    float2 hh; hh.x = packh2(v.x, v.y); hh.y = packh2(v.z, v.w);
    *(float2*)&mh8[row*68 + (c4 >> 1)] = hh;
  }
  __syncthreads();
  const float invs = 0.08838834764831845f;        // 1/sqrt(128)
  #pragma unroll
  for (int j = 0; j < 8; ++j) {
    int n = tid + (j << 8);
    const float* nr = &Nhf[(size_t)(b*PROBN + n)*64];
    float a[8];
    #pragma unroll
    for (int p = 0; p < 8; ++p) a[p] = 0.f;
    #pragma unroll 4
    for (int kq = 0; kq < 16; ++kq) {
      float4 nv = *(const float4*)&nr[kq*4];
      f16x2 n0 = f2h(nv.x), n1 = f2h(nv.y), n2 = f2h(nv.z), n3 = f2h(nv.w);
      #pragma unroll
      for (int p = 0; p < 8; ++p) {
        float4 mv = *(const float4*)&mh8[p*68 + kq*4];
        a[p] = fdot2f(f2h(mv.x), n0, a[p]);
        a[p] = fdot2f(f2h(mv.y), n1, a[p]);
        a[p] = fdot2f(f2h(mv.z), n2, a[p]);
        a[p] = fdot2f(f2h(mv.w), n3, a[p]);
      }
    }
    #pragma unroll
    for (int p = 0; p < 8; ++p) lg[p*PROBN + n] = a[p] * invs;
  }
  __syncthreads();

  int wid = tid >> 6, lane = tid & 63;
  #pragma unroll
  for (int pp = 0; pp < 2; ++pp) {
    int p = wid*2 + pp;
    const float* mrow = mask + (size_t)(b*POMO + p0 + p) * PROBN;
    float* prow = probs + (size_t)(b*POMO + p0 + p) * PROBN;
    float z[32];
    float mx = -3.0e38f;
    #pragma unroll
    for (int i4 = 0; i4 < 8; ++i4) {
      int n = 4*lane + 256*i4;
      float4 lv = *(const float4*)&lg[p*PROBN + n];
      float4 mv = *(const float4*)&mrow[n];
      float z0 = 10.f - 20.f/(__expf(2.f*lv.x)+1.f) + mv.x;
      float z1 = 10.f - 20.f/(__expf(2.f*lv.y)+1.f) + mv.y;
      float z2 = 10.f - 20.f/(__expf(2.f*lv.z)+1.f) + mv.z;
      float z3 = 10.f - 20.f/(__expf(2.f*lv.w)+1.f) + mv.w;
      z[4*i4+0] = z0; z[4*i4+1] = z1; z[4*i4+2] = z2; z[4*i4+3] = z3;
      mx = fmaxf(fmaxf(fmaxf(mx, z0), fmaxf(z1, z2)), z3);
    }
    #pragma unroll
    for (int off = 32; off > 0; off >>= 1) mx = fmaxf(mx, __shfl_xor(mx, off));
    float sum = 0.f;
    #pragma unroll
    for (int k = 0; k < 32; ++k) { z[k] = __expf(z[k] - mx); sum += z[k]; }
    #pragma unroll
    for (int off = 32; off > 0; off >>= 1) sum += __shfl_xor(sum, off);
    float rs = 1.f / sum;
    #pragma unroll
    for (int i4 = 0; i4 < 8; ++i4) {
      int n = 4*lane + 256*i4;
      *(float4*)&prow[n] = make_float4(z[4*i4+0]*rs, z[4*i4+1]*rs,
                                       z[4*i4+2]*rs, z[4*i4+3]*rs);
    }
  }
}

// ---------------------------------------------------------------------------
extern "C" void kernel_launch(void* const* d_in, const int* in_sizes, int n_in,
                              void* d_out, int out_size, void* d_ws, size_t ws_size,
                              hipStream_t stream)
{
  const float* nodes  = (const float*)d_in[0];
  const float* last   = (const float*)d_in[1];
  const float* mid    = (const float*)d_in[2];
  const float* loadv  = (const float*)d_in[3];
  const float* mask   = (const float*)d_in[4];
  const float* Wq     = (const float*)d_in[5];
  const float* Wk     = (const float*)d_in[6];
  const float* Wv     = (const float*)d_in[7];
  const float* eW     = (const float*)d_in[8];
  const float* eB     = (const float*)d_in[9];
  const float* w_gate = (const float*)d_in[10];
  float* out = (float*)d_out;
  float* ws  = (float*)d_ws;

  k_gating<<<1, 128, 0, stream>>>(mid, w_gate, ws + WS_GATES, out + BB*POMO*PROBN);
  k_experts<<<128, 256, 0, stream>>>(ws + WS_GATES, eW, eB, ws + WS_WC, ws + WS_BC);
  k_kv<<<512, 256, 0, stream>>>(nodes, Wk, Wv, ws + WS_KH, ws + WS_VHT, ws + WS_NH);
  k_q<<<128, 256, 0, stream>>>(last, loadv, Wq, ws + WS_QH);
  k_attn<<<1024, 256, 0, stream>>>(ws + WS_KH, ws + WS_VHT, ws + WS_QH, mask, ws + WS_OUT);
  k_mh<<<256, 256, 0, stream>>>(ws + WS_OUT, ws + WS_WC, ws + WS_BC, ws + WS_MH);
  k_final<<<512, 256, 0, stream>>>(ws + WS_MH, ws + WS_NH, mask, out);
}

// Round 14
// 165.166 us; speedup vs baseline: 1.3562x; 1.0114x over previous
//
#include <hip/hip_runtime.h>
#include <math.h>

#define BB    16
#define PROBN 2048
#define POMO  256
#define ED    128
#define HN    8
#define DDIM  16
#define NEXP  8

typedef _Float16 f16;
typedef f16 f16x2 __attribute__((ext_vector_type(2)));

__device__ __forceinline__ f16x2 f2h(float f) {
  union U { float f; f16x2 h; } u; u.f = f; return u.h;
}
__device__ __forceinline__ float packh2(float a, float b) {
  union U { float f; f16x2 h; } u; u.h.x = (f16)a; u.h.y = (f16)b; return u.f;
}
__device__ __forceinline__ float fdot2f(f16x2 a, f16x2 b, float c) {
#if __has_builtin(__builtin_amdgcn_fdot2)
  return __builtin_amdgcn_fdot2(a, b, c, false);
#else
  return c + (float)a.x * (float)b.x + (float)a.y * (float)b.y;
#endif
}

// ws float offsets (f16 arrays addressed as float*)
#define WS_KH    0                        // f16 K [b][n][h*16+d]    (2,097,152 floats)
#define WS_VHT   (WS_KH + 2097152)        // f16 V^T [b][h*16+d][n]  (2,097,152)
#define WS_NH    (WS_VHT + 2097152)       // f16 nodes [b][n][d]     (2,097,152)
#define WS_QH    (WS_NH + 2097152)        // f16 Q [b*POMO][d]       (262,144)
#define WS_OUT   (WS_QH + 262144)         // f16 attn out [row][64f] (262,144)
#define WS_MH    (WS_OUT + 262144)        // fp32 MoE out            (524,288)
#define WS_WC    (WS_MH + 524288)         // f16 WC pairs [b][p][c]  (131,072)
#define WS_BC    (WS_WC + 131072)         // fp32 combined bias      (2,048)
#define WS_GATES (WS_BC + 2048)           // fp32 gates              (128)

// ---------------------------------------------------------------------------
// K1: gating (top-2 softmax), gates -> ws, moe_loss -> d_out tail. FP32-EXACT.
// ---------------------------------------------------------------------------
__global__ __launch_bounds__(128) void k_gating(
    const float* __restrict__ mid, const float* __restrict__ w_gate,
    float* __restrict__ gates_ws, float* __restrict__ moe_out)
{
  __shared__ float lg[BB][NEXP];
  __shared__ float gt[BB][NEXP];
  int t = threadIdx.x;
  {
    int b = t >> 3, e = t & 7;
    float acc = 0.f;
    #pragma unroll 8
    for (int k = 0; k < ED; ++k) acc += mid[b*ED + k] * w_gate[k*NEXP + e];
    lg[b][e] = acc;
  }
  __syncthreads();
  if (t < BB) {
    int b = t;
    int i1 = 0; float v1 = lg[b][0];
    #pragma unroll
    for (int e = 1; e < NEXP; ++e) if (lg[b][e] > v1) { v1 = lg[b][e]; i1 = e; }
    int i2 = -1; float v2 = -3.0e38f;
    #pragma unroll
    for (int e = 0; e < NEXP; ++e) if (e != i1 && lg[b][e] > v2) { v2 = lg[b][e]; i2 = e; }
    float e2 = __expf(v2 - v1);          // <= 1
    float g1 = 1.f / (1.f + e2);
    #pragma unroll
    for (int e = 0; e < NEXP; ++e) gt[b][e] = 0.f;
    gt[b][i1] = g1;
    gt[b][i2] = e2 * g1;
  }
  __syncthreads();
  if (t < BB*NEXP) gates_ws[t] = gt[t >> 3][t & 7];
  if (t == 0) {
    float imp[NEXP], ldc[NEXP];
    #pragma unroll
    for (int e = 0; e < NEXP; ++e) { imp[e] = 0.f; ldc[e] = 0.f; }
    for (int b = 0; b < BB; ++b)
      #pragma unroll
      for (int e = 0; e < NEXP; ++e) {
        float g = gt[b][e];
        imp[e] += g;
        if (g > 0.f) ldc[e] += 1.f;
      }
    float im = 0.f, lm = 0.f;
    #pragma unroll
    for (int e = 0; e < NEXP; ++e) { im += imp[e]; lm += ldc[e]; }
    im *= 0.125f; lm *= 0.125f;
    float iv = 0.f, lv = 0.f;
    #pragma unroll
    for (int e = 0; e < NEXP; ++e) {
      float a = imp[e] - im; iv += a*a;
      float c = ldc[e] - lm; lv += c*c;
    }
    iv *= 0.125f; lv *= 0.125f;
    moe_out[0] = iv / (im*im + 1e-10f) + lv / (lm*lm + 1e-10f);
  }
}

// ---------------------------------------------------------------------------
// K2 v3: WCh[b] = f16 (k,k+1)-pairs of sum_e g_e*expert_W[e]; BC fp32.
// ---------------------------------------------------------------------------
__global__ __launch_bounds__(256) void k_experts(
    const float* __restrict__ gates, const float* __restrict__ eW,
    const float* __restrict__ eB, float* __restrict__ WCh, float* __restrict__ BC)
{
  __shared__ float g[NEXP];
  int tid = threadIdx.x;
  int b = blockIdx.x >> 3;
  int tile = blockIdx.x & 7;           // 8 tiles of 1024 packed floats
  if (tid < NEXP) g[tid] = gates[b*NEXP + tid];
  __syncthreads();
  int i0 = tile * 1024;
  #pragma unroll
  for (int j = 0; j < 4; ++j) {
    int pi = i0 + tid + j*256;         // packed index: p*128 + c
    int k2 = (pi >> 7) << 1;           // 2p
    int c  = pi & 127;
    float a0 = 0.f, a1 = 0.f;
    #pragma unroll
    for (int e = 0; e < NEXP; ++e) {
      a0 += g[e] * eW[e*ED*ED + k2*ED + c];
      a1 += g[e] * eW[e*ED*ED + (k2+1)*ED + c];
    }
    WCh[(size_t)b*8192 + pi] = packh2(a0, a1);
  }
  if (tile == 0 && tid < ED) {
    float a = 0.f;
    #pragma unroll
    for (int e = 0; e < NEXP; ++e) a += g[e] * eB[e*ED + tid];
    BC[b*ED + tid] = a;
  }
}

// ---------------------------------------------------------------------------
// K3 v4: K/V projection with f16 fdot2 inner loop (R10 proven).
// ---------------------------------------------------------------------------
__global__ __launch_bounds__(256) void k_kv(
    const float* __restrict__ nodes, const float* __restrict__ Wk,
    const float* __restrict__ Wv, float* __restrict__ Khf,
    float* __restrict__ VhTf, float* __restrict__ Nhf)
{
  __shared__ __align__(16) float Ash[64*66];     // 64 rows x (64 d-pairs + 2 pad)
  __shared__ __align__(16) float Wkp[16*128];    // f16 pairs [p][c]
  __shared__ __align__(16) float Wvp[16*128];
  int tid = threadIdx.x;
  int r0 = blockIdx.x * 64;
  #pragma unroll
  for (int j = 0; j < 8; ++j) {
    int idx = tid + j*256;
    int row = idx >> 5, c4 = (idx & 31) << 2;
    float4 v = *(const float4*)&nodes[(size_t)(r0 + row)*ED + c4];
    float2 nh; nh.x = packh2(v.x, v.y); nh.y = packh2(v.z, v.w);
    *(float2*)&Ash[row*66 + (c4 >> 1)] = nh;
    *(float2*)&Nhf[(size_t)(r0 + row)*64 + (c4 >> 1)] = nh;
  }
  int colg = tid & 15, rowg = tid >> 4;
  int c0 = colg << 2;              // cols c0..c0+3 and c0+64..c0+67
  float accK[4][8], accV[4][8];
  #pragma unroll
  for (int i = 0; i < 4; ++i)
    #pragma unroll
    for (int j = 0; j < 8; ++j) { accK[i][j] = 0.f; accV[i][j] = 0.f; }

  for (int kk = 0; kk < 128; kk += 32) {
    __syncthreads();
    #pragma unroll
    for (int j = 0; j < 2; ++j) {
      int wi = tid + j*256;
      int p = wi >> 5, c4 = (wi & 31) << 2;
      float4 ka = *(const float4*)&Wk[(kk + 2*p)*ED + c4];
      float4 kb = *(const float4*)&Wk[(kk + 2*p + 1)*ED + c4];
      float4 pk; pk.x = packh2(ka.x, kb.x); pk.y = packh2(ka.y, kb.y);
      pk.z = packh2(ka.z, kb.z); pk.w = packh2(ka.w, kb.w);
      *(float4*)&Wkp[p*128 + c4] = pk;
      float4 va = *(const float4*)&Wv[(kk + 2*p)*ED + c4];
      float4 vb = *(const float4*)&Wv[(kk + 2*p + 1)*ED + c4];
      float4 pv; pv.x = packh2(va.x, vb.x); pv.y = packh2(va.y, vb.y);
      pv.z = packh2(va.z, vb.z); pv.w = packh2(va.w, vb.w);
      *(float4*)&Wvp[p*128 + c4] = pv;
    }
    __syncthreads();
    #pragma unroll 4
    for (int p = 0; p < 16; ++p) {
      float ap[4];
      #pragma unroll
      for (int i = 0; i < 4; ++i) ap[i] = Ash[(rowg*4 + i)*66 + (kk >> 1) + p];
      float4 wk0 = *(float4*)&Wkp[p*128 + c0];
      float4 wk1 = *(float4*)&Wkp[p*128 + c0 + 64];
      float4 wv0 = *(float4*)&Wvp[p*128 + c0];
      float4 wv1 = *(float4*)&Wvp[p*128 + c0 + 64];
      #pragma unroll
      for (int i = 0; i < 4; ++i) {
        f16x2 ai = f2h(ap[i]);
        accK[i][0] = fdot2f(ai, f2h(wk0.x), accK[i][0]);
        accK[i][1] = fdot2f(ai, f2h(wk0.y), accK[i][1]);
        accK[i][2] = fdot2f(ai, f2h(wk0.z), accK[i][2]);
        accK[i][3] = fdot2f(ai, f2h(wk0.w), accK[i][3]);
        accK[i][4] = fdot2f(ai, f2h(wk1.x), accK[i][4]);
        accK[i][5] = fdot2f(ai, f2h(wk1.y), accK[i][5]);
        accK[i][6] = fdot2f(ai, f2h(wk1.z), accK[i][6]);
        accK[i][7] = fdot2f(ai, f2h(wk1.w), accK[i][7]);
        accV[i][0] = fdot2f(ai, f2h(wv0.x), accV[i][0]);
        accV[i][1] = fdot2f(ai, f2h(wv0.y), accV[i][1]);
        accV[i][2] = fdot2f(ai, f2h(wv0.z), accV[i][2]);
        accV[i][3] = fdot2f(ai, f2h(wv0.w), accV[i][3]);
        accV[i][4] = fdot2f(ai, f2h(wv1.x), accV[i][4]);
        accV[i][5] = fdot2f(ai, f2h(wv1.y), accV[i][5]);
        accV[i][6] = fdot2f(ai, f2h(wv1.z), accV[i][6]);
        accV[i][7] = fdot2f(ai, f2h(wv1.w), accV[i][7]);
      }
    }
  }
  // K: f16 row-major
  #pragma unroll
  for (int i = 0; i < 4; ++i) {
    size_t row = (size_t)(r0 + rowg*4 + i);
    float2 k0; k0.x = packh2(accK[i][0], accK[i][1]); k0.y = packh2(accK[i][2], accK[i][3]);
    float2 k1; k1.x = packh2(accK[i][4], accK[i][5]); k1.y = packh2(accK[i][6], accK[i][7]);
    *(float2*)&Khf[row*64 + (c0 >> 1)]      = k0;
    *(float2*)&Khf[row*64 + (c0 >> 1) + 32] = k1;
  }
  // V: f16 transposed [b][col][n] — thread's 4 rows are consecutive n
  int bb = r0 >> 11;
  int nn0 = (r0 & 2047) + rowg*4;
  #pragma unroll
  for (int j = 0; j < 8; ++j) {
    int col = (j < 4) ? (c0 + j) : (c0 + 60 + j);
    float2 vv; vv.x = packh2(accV[0][j], accV[1][j]); vv.y = packh2(accV[2][j], accV[3][j]);
    *(float2*)&VhTf[((size_t)bb*128 + col)*1024 + (nn0 >> 1)] = vv;
  }
}

// ---------------------------------------------------------------------------
// K4: Q = [last, load] @ Wq_last, fp32 compute, f16 output (R9 proven)
// ---------------------------------------------------------------------------
__global__ __launch_bounds__(256) void k_q(
    const float* __restrict__ last, const float* __restrict__ loadv,
    const float* __restrict__ Wq, float* __restrict__ Qhf)
{
  __shared__ __align__(16) float As[32*132];
  __shared__ __align__(16) float Ws[129*128];
  int tid = threadIdx.x;
  int r0 = blockIdx.x * 32;
  #pragma unroll
  for (int j = 0; j < 4; ++j) {
    int idx = tid + j*256;
    int row = idx >> 5, c4 = (idx & 31) << 2;
    *(float4*)&As[row*132 + c4] = *(const float4*)&last[(size_t)(r0 + row)*ED + c4];
  }
  if (tid < 32) As[tid*132 + 128] = loadv[r0 + tid];
  for (int idx = tid; idx < 4128; idx += 256)
    *(float4*)&Ws[idx*4] = *(const float4*)&Wq[idx*4];
  __syncthreads();

  int colg = tid & 15, rowg = tid >> 4;
  int c0 = colg << 2;
  float acc[2][8];
  #pragma unroll
  for (int i = 0; i < 2; ++i)
    #pragma unroll
    for (int j = 0; j < 8; ++j) acc[i][j] = 0.f;
  #pragma unroll 4
  for (int k = 0; k < 129; ++k) {
    float a0 = As[(rowg*2)*132 + k];
    float a1 = As[(rowg*2 + 1)*132 + k];
    float4 w0 = *(float4*)&Ws[k*128 + c0];
    float4 w1 = *(float4*)&Ws[k*128 + c0 + 64];
    acc[0][0] += a0*w0.x; acc[0][1] += a0*w0.y; acc[0][2] += a0*w0.z; acc[0][3] += a0*w0.w;
    acc[0][4] += a0*w1.x; acc[0][5] += a0*w1.y; acc[0][6] += a0*w1.z; acc[0][7] += a0*w1.w;
    acc[1][0] += a1*w0.x; acc[1][1] += a1*w0.y; acc[1][2] += a1*w0.z; acc[1][3] += a1*w0.w;
    acc[1][4] += a1*w1.x; acc[1][5] += a1*w1.y; acc[1][6] += a1*w1.z; acc[1][7] += a1*w1.w;
  }
  #pragma unroll
  for (int i = 0; i < 2; ++i) {
    size_t row = (size_t)(r0 + rowg*2 + i);
    float2 q0; q0.x = packh2(acc[i][0], acc[i][1]); q0.y = packh2(acc[i][2], acc[i][3]);
    float2 q1; q1.x = packh2(acc[i][4], acc[i][5]); q1.y = packh2(acc[i][6], acc[i][7]);
    *(float2*)&Qhf[row*64 + (c0 >> 1)]      = q0;
    *(float2*)&Qhf[row*64 + (c0 >> 1) + 32] = q1;
  }
}

// ---------------------------------------------------------------------------
// K5 v11 (R13 proven, 76.6us): f16 attention, XCD-aware 1D grid
// id = h*128 + ph*16 + b -> id%8 = b%8 (mask + K/V sharers co-locate per XCD;
// FETCH 195MB -> 29MB). Main loop FROZEN. DO NOT add: reg prefetch,
// vectorized mask map, defer-max, bigger KVBLK, split-K, 1q/thread
// (R2/R4/R5/R7 spilled; R11/R12 null). Guard: VGPR <= 64; WRITE KB-scale.
// ---------------------------------------------------------------------------
__global__ __launch_bounds__(256, 4) void k_attn(
    const float* __restrict__ Khf, const float* __restrict__ VhTf,
    const float* __restrict__ Qhf, const float* __restrict__ mask,
    float* __restrict__ Oph)
{
  __shared__ __align__(16) float kt[64*20];   // 64 key-pairs x (32 halfs + pad)
  __shared__ __align__(16) float vt[16*68];   // 16 d-rows x (128 key halfs + pad)
  int tid = threadIdx.x;
  int id = blockIdx.x;
  int h  = id >> 7;
  int ph = (id >> 4) & 7;
  int b  = id & 15;
  int nq = tid & 15;
  int pg = tid >> 4;
  int prow0 = b*POMO + ph*32 + pg*2;
  const float* maskb = mask + (size_t)prow0 * PROBN;
  const float* Kb = Khf + (size_t)b*PROBN*64 + h*8;        // float units
  const float* Vb = VhTf + ((size_t)b*128 + h*16)*1024;    // d-row stride 1024 floats

  f16x2 q[2][8];
  #pragma unroll
  for (int qi = 0; qi < 2; ++qi) {
    const float* qp = Qhf + (size_t)(prow0 + qi)*64 + h*8;
    float4 t0 = *(const float4*)&qp[0];
    float4 t1 = *(const float4*)&qp[4];
    q[qi][0] = f2h(t0.x); q[qi][1] = f2h(t0.y); q[qi][2] = f2h(t0.z); q[qi][3] = f2h(t0.w);
    q[qi][4] = f2h(t1.x); q[qi][5] = f2h(t1.y); q[qi][6] = f2h(t1.z); q[qi][7] = f2h(t1.w);
  }
  float m[2], l[2], acc[2][16];
  #pragma unroll
  for (int qi = 0; qi < 2; ++qi) {
    m[qi] = -1.0e30f; l[qi] = 0.f;
    #pragma unroll
    for (int dd = 0; dd < 16; ++dd) acc[qi][dd] = 0.f;
  }

  int srow = tid >> 1, part = tid & 1;                  // K staging: 2 thr/row
  int kws = 20*(srow >> 1) + 8*(srow & 1) + 4*part;
  int vrow = tid >> 4, vchunk = tid & 15;               // V^T staging
  int vws = 68*vrow + 4*vchunk;

  for (int tile = 0; tile < 16; ++tile) {
    int t0 = tile << 7;
    if (tile > 0) __syncthreads();
    *(float4*)&kt[kws] = *(const float4*)&Kb[(size_t)(t0 + srow)*64 + part*4];
    *(float4*)&vt[vws] = *(const float4*)&Vb[(size_t)vrow*1024 + (t0 >> 1) + vchunk*4];
    __syncthreads();

    // ---- scores (scalar mask loads, R6 style) ----
    float s[2][8];
    #pragma unroll
    for (int qi = 0; qi < 2; ++qi)
      #pragma unroll
      for (int i = 0; i < 4; ++i) {
        s[qi][2*i]   = maskb[(size_t)qi*PROBN + t0 + 2*nq + 32*i];
        s[qi][2*i+1] = maskb[(size_t)qi*PROBN + t0 + 2*nq + 32*i + 1];
      }
    #pragma unroll
    for (int i = 0; i < 4; ++i) {
      int p = nq + 16*i;
      float4 a0 = *(float4*)&kt[20*p];
      float4 a1 = *(float4*)&kt[20*p + 4];
      float4 b0 = *(float4*)&kt[20*p + 8];
      float4 b1 = *(float4*)&kt[20*p + 12];
      f16x2 ka[8] = {f2h(a0.x), f2h(a0.y), f2h(a0.z), f2h(a0.w),
                     f2h(a1.x), f2h(a1.y), f2h(a1.z), f2h(a1.w)};
      f16x2 kb[8] = {f2h(b0.x), f2h(b0.y), f2h(b0.z), f2h(b0.w),
                     f2h(b1.x), f2h(b1.y), f2h(b1.z), f2h(b1.w)};
      #pragma unroll
      for (int qi = 0; qi < 2; ++qi) {
        float d0 = 0.f, d1 = 0.f;
        #pragma unroll
        for (int j = 0; j < 8; ++j) {
          d0 = fdot2f(q[qi][j], ka[j], d0);
          d1 = fdot2f(q[qi][j], kb[j], d1);
        }
        s[qi][2*i]   += d0 * 0.25f;
        s[qi][2*i+1] += d1 * 0.25f;
      }
    }
    // ---- per-tile max merge + single unconditional rescale ----
    #pragma unroll
    for (int qi = 0; qi < 2; ++qi) {
      float tm = s[qi][0];
      #pragma unroll
      for (int i = 1; i < 8; ++i) tm = fmaxf(tm, s[qi][i]);
      float M = fmaxf(m[qi], tm);
      float c = __expf(m[qi] - M);
      m[qi] = M;
      l[qi] *= c;
      #pragma unroll
      for (int dd = 0; dd < 16; ++dd) acc[qi][dd] *= c;
    }
    // ---- exp + PV (pairwise fdot2 into fp32 acc) ----
    #pragma unroll
    for (int i = 0; i < 4; ++i) {
      int p = nq + 16*i;
      f16x2 wp0, wp1;
      {
        float w0 = __expf(s[0][2*i] - m[0]);
        float w1 = __expf(s[0][2*i+1] - m[0]);
        l[0] += w0 + w1;
        wp0.x = (f16)w0; wp0.y = (f16)w1;
        float u0 = __expf(s[1][2*i] - m[1]);
        float u1 = __expf(s[1][2*i+1] - m[1]);
        l[1] += u0 + u1;
        wp1.x = (f16)u0; wp1.y = (f16)u1;
      }
      #pragma unroll
      for (int dd = 0; dd < 16; ++dd) {
        f16x2 vh = f2h(vt[68*dd + p]);
        acc[0][dd] = fdot2f(wp0, vh, acc[0][dd]);
        acc[1][dd] = fdot2f(wp1, vh, acc[1][dd]);
      }
    }
  }

  // merge 16 stripes (tid bits 0..3, within wave)
  #pragma unroll
  for (int off = 1; off < 16; off <<= 1) {
    #pragma unroll
    for (int qi = 0; qi < 2; ++qi) {
      float m2 = __shfl_xor(m[qi], off);
      float l2 = __shfl_xor(l[qi], off);
      float M = fmaxf(m[qi], m2);
      float c1 = __expf(m[qi] - M), c2 = __expf(m2 - M);
      l[qi] = l[qi]*c1 + l2*c2;
      m[qi] = M;
      #pragma unroll
      for (int dd = 0; dd < 16; ++dd) {
        float a2 = __shfl_xor(acc[qi][dd], off);
        acc[qi][dd] = acc[qi][dd]*c1 + a2*c2;
      }
    }
  }
  // write f16-packed: lanes nq<4, compile-time indexed (rule #20)
  #pragma unroll
  for (int d4 = 0; d4 < 4; ++d4) {
    if (nq == d4) {
      #pragma unroll
      for (int qi = 0; qi < 2; ++qi) {
        float rl = 1.f / l[qi];
        float2 o;
        o.x = packh2(acc[qi][4*d4+0]*rl, acc[qi][4*d4+1]*rl);
        o.y = packh2(acc[qi][4*d4+2]*rl, acc[qi][4*d4+3]*rl);
        *(float2*)&Oph[(size_t)(prow0 + qi)*64 + h*8 + d4*2] = o;
      }
    }
  }
}

// ---------------------------------------------------------------------------
// K6 v4: MH = Oph @ WCh[b] + BC[b], f16 fdot2, grid 256.
// XCD-swizzled id = pt*16 + b -> id%8 = b%8 (WCh/Oph b-slice sharers
// co-locate per XCD).
// ---------------------------------------------------------------------------
__global__ __launch_bounds__(256) void k_mh(
    const float* __restrict__ Oph, const float* __restrict__ WCh,
    const float* __restrict__ BC, float* __restrict__ MH)
{
  __shared__ __align__(16) float Ash[16*66];    // 16 rows x 64 d-pairs (+pad)
  __shared__ __align__(16) float Wp[64*128];    // 32KB f16 pairs [p][c]
  int tid = threadIdx.x;
  int b  = blockIdx.x & 15;
  int pt = blockIdx.x >> 4;
  int r0 = b*POMO + pt*16;
  {
    int row = tid >> 4, c4 = (tid & 15) << 2;
    *(float4*)&Ash[row*66 + c4] = *(const float4*)&Oph[(size_t)(r0 + row)*64 + c4];
  }
  #pragma unroll
  for (int j = 0; j < 8; ++j) {
    int wi = tid + j*256;
    *(float4*)&Wp[wi*4] = *(const float4*)&WCh[(size_t)b*8192 + wi*4];
  }
  __syncthreads();

  int colg = tid & 15, rowg = tid >> 4;
  int c0 = colg << 2;
  float4 b0 = *(const float4*)&BC[b*ED + c0];
  float4 b1 = *(const float4*)&BC[b*ED + c0 + 64];
  float acc[8] = {b0.x, b0.y, b0.z, b0.w, b1.x, b1.y, b1.z, b1.w};
  #pragma unroll 4
  for (int p = 0; p < 64; ++p) {
    f16x2 a = f2h(Ash[rowg*66 + p]);
    float4 w0 = *(float4*)&Wp[p*128 + c0];
    float4 w1 = *(float4*)&Wp[p*128 + c0 + 64];
    acc[0] = fdot2f(a, f2h(w0.x), acc[0]);
    acc[1] = fdot2f(a, f2h(w0.y), acc[1]);
    acc[2] = fdot2f(a, f2h(w0.z), acc[2]);
    acc[3] = fdot2f(a, f2h(w0.w), acc[3]);
    acc[4] = fdot2f(a, f2h(w1.x), acc[4]);
    acc[5] = fdot2f(a, f2h(w1.y), acc[5]);
    acc[6] = fdot2f(a, f2h(w1.z), acc[6]);
    acc[7] = fdot2f(a, f2h(w1.w), acc[7]);
  }
  size_t row = (size_t)(r0 + rowg) * ED;
  *(float4*)&MH[row + c0]      = make_float4(acc[0], acc[1], acc[2], acc[3]);
  *(float4*)&MH[row + c0 + 64] = make_float4(acc[4], acc[5], acc[6], acc[7]);
}

// ---------------------------------------------------------------------------
// K7 v5: R10 body + XCD-swizzled grid: id = pt*16 + b -> id%8 = b%8, so the
// 32 blocks streaming the same 512KB Nhf b-slice co-locate per XCD (was
// spread on all 8 -> ~64MB aggregate refetch; now ~8MB).
// ---------------------------------------------------------------------------
__global__ __launch_bounds__(256) void k_final(
    const float* __restrict__ MH, const float* __restrict__ Nhf,
    const float* __restrict__ mask, float* __restrict__ probs)
{
  __shared__ __align__(16) float lg[8*PROBN];     // 64 KB
  __shared__ __align__(16) float mh8[8*68];       // f16 MH rows
  int tid = threadIdx.x;
  int b  = blockIdx.x & 15;
  int p0 = (blockIdx.x >> 4) * 8;
  {
    int row = tid >> 5, c4 = (tid & 31) << 2;
    float4 v = *(const float4*)&MH[(size_t)(b*POMO + p0 + row)*ED + c4];
    float2 hh; hh.x = packh2(v.x, v.y); hh.y = packh2(v.z, v.w);
    *(float2*)&mh8[row*68 + (c4 >> 1)] = hh;
  }
  __syncthreads();
  const float invs = 0.08838834764831845f;        // 1/sqrt(128)
  #pragma unroll
  for (int j = 0; j < 8; ++j) {
    int n = tid + (j << 8);
    const float* nr = &Nhf[(size_t)(b*PROBN + n)*64];
    float a[8];
    #pragma unroll
    for (int p = 0; p < 8; ++p) a[p] = 0.f;
    #pragma unroll 4
    for (int kq = 0; kq < 16; ++kq) {
      float4 nv = *(const float4*)&nr[kq*4];
      f16x2 n0 = f2h(nv.x), n1 = f2h(nv.y), n2 = f2h(nv.z), n3 = f2h(nv.w);
      #pragma unroll
      for (int p = 0; p < 8; ++p) {
        float4 mv = *(const float4*)&mh8[p*68 + kq*4];
        a[p] = fdot2f(f2h(mv.x), n0, a[p]);
        a[p] = fdot2f(f2h(mv.y), n1, a[p]);
        a[p] = fdot2f(f2h(mv.z), n2, a[p]);
        a[p] = fdot2f(f2h(mv.w), n3, a[p]);
      }
    }
    #pragma unroll
    for (int p = 0; p < 8; ++p) lg[p*PROBN + n] = a[p] * invs;
  }
  __syncthreads();

  int wid = tid >> 6, lane = tid & 63;
  #pragma unroll
  for (int pp = 0; pp < 2; ++pp) {
    int p = wid*2 + pp;
    const float* mrow = mask + (size_t)(b*POMO + p0 + p) * PROBN;
    float* prow = probs + (size_t)(b*POMO + p0 + p) * PROBN;
    float z[32];
    float mx = -3.0e38f;
    #pragma unroll
    for (int i4 = 0; i4 < 8; ++i4) {
      int n = 4*lane + 256*i4;
      float4 lv = *(const float4*)&lg[p*PROBN + n];
      float4 mv = *(const float4*)&mrow[n];
      float z0 = 10.f - 20.f/(__expf(2.f*lv.x)+1.f) + mv.x;
      float z1 = 10.f - 20.f/(__expf(2.f*lv.y)+1.f) + mv.y;
      float z2 = 10.f - 20.f/(__expf(2.f*lv.z)+1.f) + mv.z;
      float z3 = 10.f - 20.f/(__expf(2.f*lv.w)+1.f) + mv.w;
      z[4*i4+0] = z0; z[4*i4+1] = z1; z[4*i4+2] = z2; z[4*i4+3] = z3;
      mx = fmaxf(fmaxf(fmaxf(mx, z0), fmaxf(z1, z2)), z3);
    }
    #pragma unroll
    for (int off = 32; off > 0; off >>= 1) mx = fmaxf(mx, __shfl_xor(mx, off));
    float sum = 0.f;
    #pragma unroll
    for (int k = 0; k < 32; ++k) { z[k] = __expf(z[k] - mx); sum += z[k]; }
    #pragma unroll
    for (int off = 32; off > 0; off >>= 1) sum += __shfl_xor(sum, off);
    float rs = 1.f / sum;
    #pragma unroll
    for (int i4 = 0; i4 < 8; ++i4) {
      int n = 4*lane + 256*i4;
      *(float4*)&prow[n] = make_float4(z[4*i4+0]*rs, z[4*i4+1]*rs,
                                       z[4*i4+2]*rs, z[4*i4+3]*rs);
    }
  }
}

// ---------------------------------------------------------------------------
extern "C" void kernel_launch(void* const* d_in, const int* in_sizes, int n_in,
                              void* d_out, int out_size, void* d_ws, size_t ws_size,
                              hipStream_t stream)
{
  const float* nodes  = (const float*)d_in[0];
  const float* last   = (const float*)d_in[1];
  const float* mid    = (const float*)d_in[2];
  const float* loadv  = (const float*)d_in[3];
  const float* mask   = (const float*)d_in[4];
  const float* Wq     = (const float*)d_in[5];
  const float* Wk     = (const float*)d_in[6];
  const float* Wv     = (const float*)d_in[7];
  const float* eW     = (const float*)d_in[8];
  const float* eB     = (const float*)d_in[9];
  const float* w_gate = (const float*)d_in[10];
  float* out = (float*)d_out;
  float* ws  = (float*)d_ws;

  k_gating<<<1, 128, 0, stream>>>(mid, w_gate, ws + WS_GATES, out + BB*POMO*PROBN);
  k_experts<<<128, 256, 0, stream>>>(ws + WS_GATES, eW, eB, ws + WS_WC, ws + WS_BC);
  k_kv<<<512, 256, 0, stream>>>(nodes, Wk, Wv, ws + WS_KH, ws + WS_VHT, ws + WS_NH);
  k_q<<<128, 256, 0, stream>>>(last, loadv, Wq, ws + WS_QH);
  k_attn<<<1024, 256, 0, stream>>>(ws + WS_KH, ws + WS_VHT, ws + WS_QH, mask, ws + WS_OUT);
  k_mh<<<256, 256, 0, stream>>>(ws + WS_OUT, ws + WS_WC, ws + WS_BC, ws + WS_MH);
  k_final<<<512, 256, 0, stream>>>(ws + WS_MH, ws + WS_NH, mask, out);
}